// Round 4
// baseline (77.555 us; speedup 1.0000x reference)
//
#include <hip/hip_runtime.h>

// UVFA_text: B=256, M2=100, SV=OV=32, R=128, L=12, V=1000, E=64
// out[b,p] = sum_k relu(h2[p,k]) * u[k] + bs3.w
//   h2[p,k] = relu(base_s + Ws1_pos[p]) @ Ws2[:,k] + bs2[k]
//   base_s  = bs1 + sum_c Ws1[c*33+state[b,c]]
//   w = obj_mlp(b) * lstm_h(b);  u = Ws3 @ w
// Two kernels: pack (transpose Whh,Ws2 into d_ws) -> main (256 blocks x 1024).
// Per-thread weight slices are CONTIGUOUS rows of the transposed weights:
// one base pointer + imm offsets, so the register allocator keeps them resident.

#define B_   256
#define M2_  100
#define R_   128
#define L_   12
#define E_   64
#define NT   1024

#define X6(OP)  OP(0) OP(1) OP(2) OP(3) OP(4) OP(5)
#define X8(OP)  OP(0) OP(1) OP(2) OP(3) OP(4) OP(5) OP(6) OP(7)
#define X16(OP) X8(OP) OP(8) OP(9) OP(10) OP(11) OP(12) OP(13) OP(14) OP(15)

__device__ __forceinline__ float sigf(float x) { return 1.f / (1.f + expf(-x)); }

// ---- pack: WhhT[c][r] = Whh[r][c] (512x128), Ws2T[k][j] = Ws2[j][k] (128x128) ----
__global__ __launch_bounds__(256) void pack_kernel(
    const float* __restrict__ Whh, const float* __restrict__ Ws2, float* __restrict__ ws)
{
    int g = blockIdx.x * 256 + threadIdx.x;
    if (g < 512 * 128) {
        int c = g >> 7, r = g & 127;
        ws[g] = Whh[r * 512 + c];                 // WhhT at ws[0]
    } else if (g < 512 * 128 + 128 * 128) {
        int g2 = g - 512 * 128;
        int k = g2 >> 7, j = g2 & 127;
        ws[512 * 128 + g2] = Ws2[j * 128 + k];    // Ws2T at ws[65536]
    }
}

__global__ __launch_bounds__(NT, 4) void uvfa_kernel(
    const int* __restrict__ state, const int* __restrict__ obj, const int* __restrict__ text,
    const float* __restrict__ Ws1, const float* __restrict__ bs1,
    const float* __restrict__ bs2, const float* __restrict__ Ws3, const float* __restrict__ bs3,
    const float* __restrict__ Wo1, const float* __restrict__ bo1,
    const float* __restrict__ Wo2, const float* __restrict__ bo2,
    const float* __restrict__ Wo3, const float* __restrict__ bo3,
    const float* __restrict__ emb, const float* __restrict__ Wih,
    const float* __restrict__ b_lstm,
    const float* __restrict__ WhhT, const float* __restrict__ Ws2T,
    float* __restrict__ out)
{
    const int b   = blockIdx.x;
    const int tid = threadIdx.x;

    // big: phase 1 = xw[12][512] (6144) + xemb[12][64]; phase 2 = h1[100][128]
    __shared__ __align__(16) float big[12800];   // 51.2 KB
    __shared__ float part[NT];
    __shared__ float hbuf[R_];
    __shared__ float redw[16][50];
    __shared__ float tmp[R_], tmp2[R_], wbuf[R_], ubuf[R_], bsbuf[R_];
    __shared__ int   idx_o[M2_], idx_s[M2_], tids[L_];
    __shared__ float c0s;

    float* xw   = big;          // [12][512]
    float* xemb = big + 6144;   // [12][64]

    // ---------- P1: ids, init ----------
    if (tid < L_) tids[tid] = text[b * L_ + tid];
    if (tid >= 128 && tid < 128 + M2_) idx_o[tid - 128] = obj[b * M2_ + tid - 128];
    if (tid >= 256 && tid < 256 + M2_) idx_s[tid - 256] = state[b * M2_ + tid - 256];
    if (tid < R_) hbuf[tid] = 0.f;
    __syncthreads();
    if (tid < L_ * E_) xemb[tid] = emb[tids[tid >> 6] * E_ + (tid & 63)];
    __syncthreads();

    // ---------- P2: xw[t][col] = b_lstm[col] + x_t @ Wih ----------
    {
        const int col = tid & 511, th = tid >> 9;
        float bl = b_lstm[col];
        #define DA(i) float a##i = bl;
        X6(DA)
        const float* xe = xemb + (th * 6) * E_;
        for (int e = 0; e < E_; ++e) {
            float we = Wih[e * 512 + col];
            #define FA(i) a##i = fmaf(xe[(i) * E_ + e], we, a##i);
            X6(FA)
        }
        #define SA(i) xw[(th * 6 + (i)) * 512 + col] = a##i;
        X6(SA)
    }

    // ---------- Whh half-column: 16 contiguous float4 from ONE base ----------
    const int colW = tid >> 1, half = tid & 1;
    const float4* wp = reinterpret_cast<const float4*>(WhhT + colW * 128 + half * 64);
    #define DW(i) float4 w##i = wp[i];
    X16(DW)
    __syncthreads();   // xw + hbuf ready

    // ---------- P3: LSTM recurrence ----------
    float cst = 0.f;
    {
        const float4* hb4 = reinterpret_cast<const float4*>(hbuf) + 16 * half;
        #define FW(i) { float4 h4 = hb4[i]; \
            s0 = fmaf(h4.x, w##i.x, s0); s1 = fmaf(h4.y, w##i.y, s1); \
            s2 = fmaf(h4.z, w##i.z, s2); s3 = fmaf(h4.w, w##i.w, s3); }
        for (int t = 0; t < L_; ++t) {
            float s0 = half ? 0.f : xw[t * 512 + colW];
            float s1 = 0.f, s2 = 0.f, s3 = 0.f;
            X16(FW)
            float s = (s0 + s1) + (s2 + s3);
            s += __shfl_xor(s, 1, 64);
            if (!half) part[colW] = s;
            __syncthreads();
            if (tid < R_) {
                float gi = part[tid], gf = part[R_ + tid], gg = part[2 * R_ + tid], go = part[3 * R_ + tid];
                cst = sigf(gf) * cst + sigf(gi) * tanhf(gg);
                hbuf[tid] = sigf(go) * tanhf(cst);
            }
            __syncthreads();
        }
    }

    // ---------- P4: object MLP ----------
    const int k = tid & 127, qq = tid >> 7;
    {
        float acc = 0.f;
        int c0i = qq * 13, c1i = c0i + 13 < M2_ ? c0i + 13 : M2_;
        for (int c = c0i; c < c1i; ++c)
            acc += Wo1[(c * 32 + idx_o[c]) * R_ + k];
        part[qq * R_ + k] = acc;
    }
    __syncthreads();
    if (tid < R_) {
        float a = bo1[tid];
        #pragma unroll
        for (int q = 0; q < 8; ++q) a += part[q * R_ + tid];
        tmp[tid] = fmaxf(a, 0.f);
    }
    __syncthreads();
    if (tid < 512) {
        float s0 = 0.f, s1 = 0.f, s2 = 0.f, s3 = 0.f;
        int j0 = qq * 32;
        #pragma unroll
        for (int j = 0; j < 32; j += 4) {
            s0 = fmaf(tmp[j0 + j + 0], Wo2[(j0 + j + 0) * R_ + k], s0);
            s1 = fmaf(tmp[j0 + j + 1], Wo2[(j0 + j + 1) * R_ + k], s1);
            s2 = fmaf(tmp[j0 + j + 2], Wo2[(j0 + j + 2) * R_ + k], s2);
            s3 = fmaf(tmp[j0 + j + 3], Wo2[(j0 + j + 3) * R_ + k], s3);
        }
        part[qq * R_ + k] = (s0 + s1) + (s2 + s3);
    }
    __syncthreads();
    if (tid < R_)
        tmp2[tid] = fmaxf(bo2[tid] + part[tid] + part[R_ + tid] + part[2 * R_ + tid] + part[3 * R_ + tid], 0.f);
    __syncthreads();
    if (tid < 512) {
        float s0 = 0.f, s1 = 0.f, s2 = 0.f, s3 = 0.f;
        int j0 = qq * 32;
        #pragma unroll
        for (int j = 0; j < 32; j += 4) {
            s0 = fmaf(tmp2[j0 + j + 0], Wo3[(j0 + j + 0) * R_ + k], s0);
            s1 = fmaf(tmp2[j0 + j + 1], Wo3[(j0 + j + 1) * R_ + k], s1);
            s2 = fmaf(tmp2[j0 + j + 2], Wo3[(j0 + j + 2) * R_ + k], s2);
            s3 = fmaf(tmp2[j0 + j + 3], Wo3[(j0 + j + 3) * R_ + k], s3);
        }
        part[qq * R_ + k] = (s0 + s1) + (s2 + s3);
    }
    __syncthreads();
    if (tid < R_)
        wbuf[tid] = (bo3[tid] + part[tid] + part[R_ + tid] + part[2 * R_ + tid] + part[3 * R_ + tid]) * hbuf[tid];
    __syncthreads();

    // ---------- P5: u = Ws3 @ w ; c0 = bs3 . w ----------
    if (tid < 512) {
        float s0 = 0.f, s1 = 0.f, s2 = 0.f, s3 = 0.f;
        const float4* w4 = reinterpret_cast<const float4*>(&Ws3[k * R_ + qq * 32]);
        #pragma unroll
        for (int jj = 0; jj < 8; ++jj) {
            float4 v = w4[jj];
            int j0 = qq * 32 + jj * 4;
            s0 = fmaf(v.x, wbuf[j0 + 0], s0);
            s1 = fmaf(v.y, wbuf[j0 + 1], s1);
            s2 = fmaf(v.z, wbuf[j0 + 2], s2);
            s3 = fmaf(v.w, wbuf[j0 + 3], s3);
        }
        part[qq * R_ + k] = (s0 + s1) + (s2 + s3);
    }
    if (tid >= 960) {
        int j = tid - 960;
        float s = bs3[j] * wbuf[j] + bs3[j + 64] * wbuf[j + 64];
        s += __shfl_down(s, 32, 64);
        s += __shfl_down(s, 16, 64);
        s += __shfl_down(s, 8, 64);
        s += __shfl_down(s, 4, 64);
        s += __shfl_down(s, 2, 64);
        s += __shfl_down(s, 1, 64);
        if (j == 0) c0s = s;
    }
    __syncthreads();
    if (tid < R_) ubuf[tid] = part[tid] + part[R_ + tid] + part[2 * R_ + tid] + part[3 * R_ + tid];

    // ---------- P6: base_s gather ----------
    {
        float acc = 0.f;
        int c0i = qq * 13, c1i = c0i + 13 < M2_ ? c0i + 13 : M2_;
        for (int c = c0i; c < c1i; ++c)
            acc += Ws1[(c * 33 + idx_s[c]) * R_ + k];
        part[qq * R_ + k] = acc;
    }
    __syncthreads();
    if (tid < R_) {
        float a = bs1[tid];
        #pragma unroll
        for (int q = 0; q < 8; ++q) a += part[q * R_ + tid];
        bsbuf[tid] = a;
    }

    // ---------- Ws2T quarter-row: 8 contiguous float4 from ONE base (rotated order) ----------
    const int k2 = (tid >> 2) & 127, q2 = tid & 3;
    const float4* cp = reinterpret_cast<const float4*>(Ws2T + k2 * 128 + q2 * 32);
    #define DC(i) float4 wc##i = cp[((i) + 2 * q2) & 7];
    X8(DC)
    __syncthreads();   // bsbuf + ubuf ready; xw dead

    // ---------- P7: h1[p][k] = relu(bsbuf[k] + Ws1_pos[p][k]) ----------
    for (int i = tid; i < M2_ * R_; i += NT)
        big[i] = fmaxf(bsbuf[i & 127] + Ws1[((i >> 7) * 33 + 32) * R_ + (i & 127)], 0.f);
    __syncthreads();

    // ---------- P8: main 100x128x128, 2 positions in flight, barrier-free ----------
    const int   pp   = tid >> 9;
    const int   wid  = tid >> 6;
    const float uk   = ubuf[k2];
    const float bs2k = bs2[k2];
    const float4* h1f4 = reinterpret_cast<const float4*>(big);
    #define FC(i) { float4 h4 = rowp[(((i) + 2 * q2) & 7)]; \
        s0 = fmaf(h4.x, wc##i.x, s0); s1 = fmaf(h4.y, wc##i.y, s1); \
        s2 = fmaf(h4.z, wc##i.z, s2); s3 = fmaf(h4.w, wc##i.w, s3); }
    #pragma unroll 2
    for (int it = 0; it < 50; ++it) {
        int p = 2 * it + pp;
        const float4* rowp = h1f4 + p * 32 + q2 * 8;
        float s0 = 0.f, s1 = 0.f, s2 = 0.f, s3 = 0.f;
        X8(FC)
        float s = (s0 + s1) + (s2 + s3);
        s += __shfl_xor(s, 1, 64);
        s += __shfl_xor(s, 2, 64);          // quad combined: full h2[p][k2]
        float val = fmaxf(s + bs2k, 0.f) * uk;
        val += __shfl_down(val, 32, 64);
        val += __shfl_down(val, 16, 64);
        val += __shfl_down(val, 8, 64);
        val += __shfl_down(val, 4, 64);
        if ((tid & 63) == 0) redw[wid][it] = val;
    }
    __syncthreads();

    // ---------- P9: combine 8 wave-partials per position ----------
    if (tid < M2_) {
        int it = tid >> 1, pg = tid & 1;
        float o = c0s;
        #pragma unroll
        for (int w = 0; w < 8; ++w) o += redw[pg * 8 + w][it];
        out[b * M2_ + tid] = o;
    }
}

extern "C" void kernel_launch(void* const* d_in, const int* in_sizes, int n_in,
                              void* d_out, int out_size, void* d_ws, size_t ws_size,
                              hipStream_t stream) {
    const int*   state  = (const int*)d_in[0];
    const int*   obj    = (const int*)d_in[1];
    const int*   text   = (const int*)d_in[2];
    const float* Ws1    = (const float*)d_in[3];
    const float* bs1    = (const float*)d_in[4];
    const float* Ws2    = (const float*)d_in[5];
    const float* bs2    = (const float*)d_in[6];
    const float* Ws3    = (const float*)d_in[7];
    const float* bs3    = (const float*)d_in[8];
    const float* Wo1    = (const float*)d_in[9];
    const float* bo1    = (const float*)d_in[10];
    const float* Wo2    = (const float*)d_in[11];
    const float* bo2    = (const float*)d_in[12];
    const float* Wo3    = (const float*)d_in[13];
    const float* bo3    = (const float*)d_in[14];
    const float* emb    = (const float*)d_in[15];
    const float* Wih    = (const float*)d_in[16];
    const float* Whh    = (const float*)d_in[17];
    const float* b_lstm = (const float*)d_in[18];
    float* out = (float*)d_out;

    float* ws   = (float*)d_ws;
    float* WhhT = ws;            // 512*128
    float* Ws2T = ws + 65536;    // 128*128

    hipLaunchKernelGGL(pack_kernel, dim3(320), dim3(256), 0, stream, Whh, Ws2, ws);
    hipLaunchKernelGGL(uvfa_kernel, dim3(B_), dim3(NT), 0, stream,
                       state, obj, text, Ws1, bs1, bs2, Ws3, bs3,
                       Wo1, bo1, Wo2, bo2, Wo3, bo3, emb, Wih, b_lstm,
                       WhhT, Ws2T, out);
}

// Round 5
// 71.143 us; speedup vs baseline: 1.0901x; 1.0901x over previous
//
#include <hip/hip_runtime.h>

// UVFA_text: B=256, M2=100, SV=OV=32, R=128, L=12, V=1000, E=64
// out[b,p] = sum_k relu(h2[p,k]) * u[k] + bs3.w
//   h2[p,k] = relu(base_s + Ws1_pos[p]) @ Ws2[:,k] + bs2[k]
//   base_s  = bs1 + sum_c Ws1[c*33+state[b,c]]
//   w = obj_mlp(b) * lstm_h(b);  u = Ws3 @ w
// 512 threads/block, 256 blocks. Weights pinned in VGPRs via opaque asm
// (defeats load rematerialization). Main matmul: K_BLOCK=4 -> 4x fewer LDS reads.

#define B_   256
#define M2_  100
#define R_   128
#define L_   12
#define E_   64
#define NT   512

#define X8(OP)  OP(0) OP(1) OP(2) OP(3) OP(4) OP(5) OP(6) OP(7)
#define X12(OP) X8(OP) OP(8) OP(9) OP(10) OP(11)
#define X32(OP) X12(OP) OP(12) OP(13) OP(14) OP(15) OP(16) OP(17) OP(18) OP(19) \
                OP(20) OP(21) OP(22) OP(23) OP(24) OP(25) OP(26) OP(27) \
                OP(28) OP(29) OP(30) OP(31)

// Pin a float4 into VGPRs: def becomes opaque asm -> not rematerializable.
#define OPQ4(v) asm volatile("" : "+v"(v.x), "+v"(v.y), "+v"(v.z), "+v"(v.w));

__device__ __forceinline__ float sigf(float x) { return 1.f / (1.f + expf(-x)); }

// ---- pack: WhhT[c][r] = Whh[r][c] (512x128), Ws2T[k][j] = Ws2[j][k] (128x128) ----
__global__ __launch_bounds__(256) void pack_kernel(
    const float* __restrict__ Whh, const float* __restrict__ Ws2, float* __restrict__ ws)
{
    int g = blockIdx.x * 256 + threadIdx.x;
    if (g < 512 * 128) {
        int c = g >> 7, r = g & 127;
        ws[g] = Whh[r * 512 + c];                 // WhhT at ws[0]
    } else if (g < 512 * 128 + 128 * 128) {
        int g2 = g - 512 * 128;
        int k = g2 >> 7, j = g2 & 127;
        ws[512 * 128 + g2] = Ws2[j * 128 + k];    // Ws2T at ws[65536]
    }
}

__global__ __launch_bounds__(NT, 2) void uvfa_kernel(
    const int* __restrict__ state, const int* __restrict__ obj, const int* __restrict__ text,
    const float* __restrict__ Ws1, const float* __restrict__ bs1,
    const float* __restrict__ bs2, const float* __restrict__ Ws3, const float* __restrict__ bs3,
    const float* __restrict__ Wo1, const float* __restrict__ bo1,
    const float* __restrict__ Wo2, const float* __restrict__ bo2,
    const float* __restrict__ Wo3, const float* __restrict__ bo3,
    const float* __restrict__ emb, const float* __restrict__ Wih,
    const float* __restrict__ b_lstm,
    const float* __restrict__ WhhT, const float* __restrict__ Ws2T,
    float* __restrict__ out)
{
    const int b   = blockIdx.x;
    const int tid = threadIdx.x;

    // big: phase 1 = xw[12][512] (6144) + xemb[12][64]; phase 2 = h1 swizzled [100][128]
    __shared__ __align__(16) float big[12800];               // 51.2 KB
    __shared__ __align__(16) float part[NT];
    __shared__ __align__(16) float hbuf[R_];
    __shared__ float redw[8][25];
    __shared__ __align__(16) float tmp[R_], tmp2[R_], wbuf[R_], ubuf[R_], bsw[R_];
    __shared__ int   idx_o[M2_], idx_s[M2_], tids[L_];
    __shared__ float c0s;

    float* xw   = big;          // [12][512]
    float* xemb = big + 6144;   // [12][64]

    // ---------- P1: ids, init ----------
    if (tid < M2_) idx_o[tid] = obj[b * M2_ + tid];
    if (tid >= 128 && tid < 128 + M2_) idx_s[tid - 128] = state[b * M2_ + tid - 128];
    if (tid >= 256 && tid < 256 + L_) tids[tid - 256] = text[b * L_ + tid - 256];
    if (tid >= 384) hbuf[tid - 384] = 0.f;
    __syncthreads();
    for (int i = tid; i < L_ * E_; i += NT)
        xemb[i] = emb[tids[i >> 6] * E_ + (i & 63)];
    __syncthreads();

    // ---------- P2: xw[t][col] = b_lstm[col] + x_t @ Wih (thread = col) ----------
    {
        float bl = b_lstm[tid];
        #define DA(i) float a##i = bl;
        X12(DA)
        for (int e = 0; e < E_; ++e) {
            float we = Wih[e * 512 + tid];
            #define FA(i) a##i = fmaf(xemb[(i) * E_ + e], we, a##i);
            X12(FA)
        }
        #define SA(i) xw[(i) * 512 + tid] = a##i;
        X12(SA)
    }

    // ---------- Whh full column (128 floats = 32 float4), pinned ----------
    {
        const float4* wp = reinterpret_cast<const float4*>(WhhT + tid * 128);
        #define DWL(i) float4 wl##i = wp[i];
        X32(DWL)
        #define OPL(i) OPQ4(wl##i)
        X32(OPL)
        __syncthreads();   // xw + hbuf ready

        // ---------- P3: LSTM recurrence (thread = full gate column, no shuffles) ----------
        float cst = 0.f;
        const float4* hb4 = reinterpret_cast<const float4*>(hbuf);
        for (int t = 0; t < L_; ++t) {
            float s0 = xw[t * 512 + tid], s1 = 0.f, s2 = 0.f, s3 = 0.f;
            #define FL(i) { float4 h4 = hb4[i]; \
                s0 = fmaf(h4.x, wl##i.x, s0); s1 = fmaf(h4.y, wl##i.y, s1); \
                s2 = fmaf(h4.z, wl##i.z, s2); s3 = fmaf(h4.w, wl##i.w, s3); }
            X32(FL)
            part[tid] = (s0 + s1) + (s2 + s3);
            __syncthreads();
            if (tid < R_) {
                float gi = part[tid], gf = part[R_ + tid], gg = part[2 * R_ + tid], go = part[3 * R_ + tid];
                cst = sigf(gf) * cst + sigf(gi) * tanhf(gg);
                hbuf[tid] = sigf(go) * tanhf(cst);
            }
            __syncthreads();
        }
    }

    // ---------- P4: object MLP ----------
    const int k = tid & 127, qq = tid >> 7;   // qq 0..3
    {
        float acc = 0.f;
        #pragma unroll 5
        for (int c = qq * 25; c < qq * 25 + 25; ++c)
            acc += Wo1[(c * 32 + idx_o[c]) * R_ + k];
        part[qq * R_ + k] = acc;
    }
    __syncthreads();
    if (tid < R_)
        tmp[tid] = fmaxf(bo1[tid] + part[tid] + part[R_ + tid] + part[2 * R_ + tid] + part[3 * R_ + tid], 0.f);
    __syncthreads();
    {
        float s0 = 0.f, s1 = 0.f, s2 = 0.f, s3 = 0.f;
        int j0 = qq * 32;
        #pragma unroll
        for (int j = 0; j < 32; j += 4) {
            s0 = fmaf(tmp[j0 + j + 0], Wo2[(j0 + j + 0) * R_ + k], s0);
            s1 = fmaf(tmp[j0 + j + 1], Wo2[(j0 + j + 1) * R_ + k], s1);
            s2 = fmaf(tmp[j0 + j + 2], Wo2[(j0 + j + 2) * R_ + k], s2);
            s3 = fmaf(tmp[j0 + j + 3], Wo2[(j0 + j + 3) * R_ + k], s3);
        }
        part[qq * R_ + k] = (s0 + s1) + (s2 + s3);
    }
    __syncthreads();
    if (tid < R_)
        tmp2[tid] = fmaxf(bo2[tid] + part[tid] + part[R_ + tid] + part[2 * R_ + tid] + part[3 * R_ + tid], 0.f);
    __syncthreads();
    {
        float s0 = 0.f, s1 = 0.f, s2 = 0.f, s3 = 0.f;
        int j0 = qq * 32;
        #pragma unroll
        for (int j = 0; j < 32; j += 4) {
            s0 = fmaf(tmp2[j0 + j + 0], Wo3[(j0 + j + 0) * R_ + k], s0);
            s1 = fmaf(tmp2[j0 + j + 1], Wo3[(j0 + j + 1) * R_ + k], s1);
            s2 = fmaf(tmp2[j0 + j + 2], Wo3[(j0 + j + 2) * R_ + k], s2);
            s3 = fmaf(tmp2[j0 + j + 3], Wo3[(j0 + j + 3) * R_ + k], s3);
        }
        part[qq * R_ + k] = (s0 + s1) + (s2 + s3);
    }
    __syncthreads();
    if (tid < R_)
        wbuf[tid] = (bo3[tid] + part[tid] + part[R_ + tid] + part[2 * R_ + tid] + part[3 * R_ + tid]) * hbuf[tid];
    __syncthreads();

    // ---------- P5: u = Ws3 @ w ; c0 = bs3 . w ----------
    {
        float s0 = 0.f, s1 = 0.f, s2 = 0.f, s3 = 0.f;
        const float4* w4 = reinterpret_cast<const float4*>(&Ws3[k * R_ + qq * 32]);
        #pragma unroll
        for (int jj = 0; jj < 8; ++jj) {
            float4 v = w4[jj];
            int j0 = qq * 32 + jj * 4;
            s0 = fmaf(v.x, wbuf[j0 + 0], s0);
            s1 = fmaf(v.y, wbuf[j0 + 1], s1);
            s2 = fmaf(v.z, wbuf[j0 + 2], s2);
            s3 = fmaf(v.w, wbuf[j0 + 3], s3);
        }
        part[qq * R_ + k] = (s0 + s1) + (s2 + s3);
    }
    __syncthreads();
    if (tid < R_) ubuf[tid] = part[tid] + part[R_ + tid] + part[2 * R_ + tid] + part[3 * R_ + tid];
    if (tid >= 448) {
        int j = tid - 448;
        float s = bs3[j] * wbuf[j] + bs3[j + 64] * wbuf[j + 64];
        s += __shfl_down(s, 32, 64);
        s += __shfl_down(s, 16, 64);
        s += __shfl_down(s, 8, 64);
        s += __shfl_down(s, 4, 64);
        s += __shfl_down(s, 2, 64);
        s += __shfl_down(s, 1, 64);
        if (j == 0) c0s = s;
    }
    __syncthreads();

    // ---------- P6: base_s gather; store SWIZZLED: j=(q,i,c) -> t = i*16+q*4+c ----------
    {
        float acc = 0.f;
        #pragma unroll 5
        for (int c = qq * 25; c < qq * 25 + 25; ++c)
            acc += Ws1[(c * 33 + idx_s[c]) * R_ + k];
        part[qq * R_ + k] = acc;
    }
    __syncthreads();
    if (tid < R_) {
        float a = bs1[tid] + part[tid] + part[R_ + tid] + part[2 * R_ + tid] + part[3 * R_ + tid];
        int t = (((tid & 31) >> 2) << 4) + ((tid >> 5) << 2) + (tid & 3);
        bsw[t] = a;
    }

    // ---------- P8 weights: 4 k-rows x 32 j, pinned (32 float4) ----------
    const int kg = (tid >> 2) & 31, q = tid & 3, po = tid >> 7;
    const float4* wb0 = reinterpret_cast<const float4*>(Ws2T + (kg * 4 + 0) * 128 + q * 32);
    const float4* wb1 = reinterpret_cast<const float4*>(Ws2T + (kg * 4 + 1) * 128 + q * 32);
    const float4* wb2 = reinterpret_cast<const float4*>(Ws2T + (kg * 4 + 2) * 128 + q * 32);
    const float4* wb3 = reinterpret_cast<const float4*>(Ws2T + (kg * 4 + 3) * 128 + q * 32);
    #define DWA(i) float4 wa##i = wb0[i];
    #define DWB(i) float4 wbb##i = wb1[i];
    #define DWC(i) float4 wcc##i = wb2[i];
    #define DWD(i) float4 wdd##i = wb3[i];
    X8(DWA) X8(DWB) X8(DWC) X8(DWD)
    #define OPA(i) OPQ4(wa##i)
    #define OPB(i) OPQ4(wbb##i)
    #define OPC(i) OPQ4(wcc##i)
    #define OPD(i) OPQ4(wdd##i)
    X8(OPA) X8(OPB) X8(OPC) X8(OPD)
    __syncthreads();   // bsw ready; xw dead

    // ---------- P7: h1 swizzled: big[p*128 + t] = relu(bsw[t] + Ws1_pos[p][j(t)]) ----------
    for (int s = tid; s < M2_ * R_; s += NT) {
        int p = s >> 7, t = s & 127;
        int j = ((t >> 2) & 3) * 32 + (t >> 4) * 4 + (t & 3);
        big[s] = fmaxf(bsw[t] + Ws1[(p * 33 + 32) * R_ + j], 0.f);
    }
    __syncthreads();

    // ---------- P8: 100x128x128, K_BLOCK=4, conflict-free broadcast reads ----------
    const float u0 = ubuf[kg * 4 + 0], u1 = ubuf[kg * 4 + 1];
    const float u2 = ubuf[kg * 4 + 2], u3 = ubuf[kg * 4 + 3];
    const float t0 = bs2[kg * 4 + 0], t1 = bs2[kg * 4 + 1];
    const float t2 = bs2[kg * 4 + 2], t3 = bs2[kg * 4 + 3];
    const float4* big4 = reinterpret_cast<const float4*>(big);
    for (int it = 0; it < 25; ++it) {
        int p = it * 4 + po;
        const float4* hrow = big4 + p * 32 + q;   // read [i*4]: banks 4q..4q+3, 16-way bcast
        float a0 = 0.f, a1 = 0.f, a2 = 0.f, a3 = 0.f;
        #define FP(i) { float4 h4 = hrow[4 * (i)]; \
            a0 = fmaf(h4.x, wa##i.x,  a0); a0 = fmaf(h4.y, wa##i.y,  a0); \
            a0 = fmaf(h4.z, wa##i.z,  a0); a0 = fmaf(h4.w, wa##i.w,  a0); \
            a1 = fmaf(h4.x, wbb##i.x, a1); a1 = fmaf(h4.y, wbb##i.y, a1); \
            a1 = fmaf(h4.z, wbb##i.z, a1); a1 = fmaf(h4.w, wbb##i.w, a1); \
            a2 = fmaf(h4.x, wcc##i.x, a2); a2 = fmaf(h4.y, wcc##i.y, a2); \
            a2 = fmaf(h4.z, wcc##i.z, a2); a2 = fmaf(h4.w, wcc##i.w, a2); \
            a3 = fmaf(h4.x, wdd##i.x, a3); a3 = fmaf(h4.y, wdd##i.y, a3); \
            a3 = fmaf(h4.z, wdd##i.z, a3); a3 = fmaf(h4.w, wdd##i.w, a3); }
        X8(FP)
        // j-reduction over the 4 q-lanes (quad)
        a0 += __shfl_xor(a0, 1, 64); a0 += __shfl_xor(a0, 2, 64);
        a1 += __shfl_xor(a1, 1, 64); a1 += __shfl_xor(a1, 2, 64);
        a2 += __shfl_xor(a2, 1, 64); a2 += __shfl_xor(a2, 2, 64);
        a3 += __shfl_xor(a3, 1, 64); a3 += __shfl_xor(a3, 2, 64);
        float val = fmaxf(a0 + t0, 0.f) * u0 + fmaxf(a1 + t1, 0.f) * u1
                  + fmaxf(a2 + t2, 0.f) * u2 + fmaxf(a3 + t3, 0.f) * u3;
        // k-reduction over 16 kg's in the wave
        val += __shfl_down(val, 4, 64);
        val += __shfl_down(val, 8, 64);
        val += __shfl_down(val, 16, 64);
        val += __shfl_down(val, 32, 64);
        if ((tid & 63) == 0) redw[tid >> 6][it] = val;
    }
    __syncthreads();

    // ---------- P9: combine 2 wave-partials per position ----------
    if (tid < M2_) {
        int it = tid >> 2, pg = tid & 3;
        out[b * M2_ + tid] = c0s + redw[pg * 2][it] + redw[pg * 2 + 1][it];
    }
}

extern "C" void kernel_launch(void* const* d_in, const int* in_sizes, int n_in,
                              void* d_out, int out_size, void* d_ws, size_t ws_size,
                              hipStream_t stream) {
    const int*   state  = (const int*)d_in[0];
    const int*   obj    = (const int*)d_in[1];
    const int*   text   = (const int*)d_in[2];
    const float* Ws1    = (const float*)d_in[3];
    const float* bs1    = (const float*)d_in[4];
    const float* Ws2    = (const float*)d_in[5];
    const float* bs2    = (const float*)d_in[6];
    const float* Ws3    = (const float*)d_in[7];
    const float* bs3    = (const float*)d_in[8];
    const float* Wo1    = (const float*)d_in[9];
    const float* bo1    = (const float*)d_in[10];
    const float* Wo2    = (const float*)d_in[11];
    const float* bo2    = (const float*)d_in[12];
    const float* Wo3    = (const float*)d_in[13];
    const float* bo3    = (const float*)d_in[14];
    const float* emb    = (const float*)d_in[15];
    const float* Wih    = (const float*)d_in[16];
    const float* Whh    = (const float*)d_in[17];
    const float* b_lstm = (const float*)d_in[18];
    float* out = (float*)d_out;

    float* ws   = (float*)d_ws;
    float* WhhT = ws;            // 512*128
    float* Ws2T = ws + 65536;    // 128*128

    hipLaunchKernelGGL(pack_kernel, dim3(320), dim3(256), 0, stream, Whh, Ws2, ws);
    hipLaunchKernelGGL(uvfa_kernel, dim3(B_), dim3(NT), 0, stream,
                       state, obj, text, Ws1, bs1, bs2, Ws3, bs3,
                       Wo1, bo1, Wo2, bo2, Wo3, bo3, emb, Wih, b_lstm,
                       WhhT, Ws2T, out);
}

// Round 6
// 70.806 us; speedup vs baseline: 1.0953x; 1.0048x over previous
//
#include <hip/hip_runtime.h>

// UVFA_text: B=256, M2=100, SV=OV=32, R=128, L=12, V=1000, E=64
// out[b,p] = sum_k relu(h2[p,k]) * u[k] + bs3.w
//   h2[p,k] = relu(base_s + Ws1_pos[p]) @ Ws2[:,k] + bs2[k]
//   base_s  = bs1 + sum_c Ws1[c*33+state[b,c]]
//   w = obj_mlp(b) * lstm_h(b);  u[j] = sum_k Ws3[j,k] w[k]
// One kernel, 256 blocks x 1024 threads, VGPR cap 128 (launch_bounds 1024,4):
// every phase's live register demand <= ~100 so weight slices (64 VGPRs) stay
// resident with zero spill. No pack kernel: weights loaded k-fast from Ws2 and
// strided-coalesced from Whh.

#define B_   256
#define M2_  100
#define R_   128
#define L_   12
#define E_   64
#define NT   1024

#define X6(OP)  OP(0) OP(1) OP(2) OP(3) OP(4) OP(5)
#define X8(OP)  OP(0) OP(1) OP(2) OP(3) OP(4) OP(5) OP(6) OP(7)
#define X12(OP) X8(OP) OP(8) OP(9) OP(10) OP(11)
#define X16(OP) X12(OP) OP(12) OP(13) OP(14) OP(15)

// keep a loaded float4 from being rematerialized
#define OPQ4(v) asm volatile("" : "+v"(v.x), "+v"(v.y), "+v"(v.z), "+v"(v.w));

__device__ __forceinline__ float sigf(float x) { return 1.f / (1.f + expf(-x)); }

__global__ __launch_bounds__(NT, 4) void uvfa_kernel(
    const int* __restrict__ state, const int* __restrict__ obj, const int* __restrict__ text,
    const float* __restrict__ Ws1, const float* __restrict__ bs1,
    const float* __restrict__ Ws2, const float* __restrict__ bs2,
    const float* __restrict__ Ws3, const float* __restrict__ bs3,
    const float* __restrict__ Wo1, const float* __restrict__ bo1,
    const float* __restrict__ Wo2, const float* __restrict__ bo2,
    const float* __restrict__ Wo3, const float* __restrict__ bo3,
    const float* __restrict__ emb, const float* __restrict__ Wih,
    const float* __restrict__ Whh, const float* __restrict__ b_lstm,
    float* __restrict__ out)
{
    const int b   = blockIdx.x;
    const int tid = threadIdx.x;

    // big: phase 1 = xw[12][512] + xemb[12][64]; phase 2 = h1[100][128]
    __shared__ __align__(16) float big[12800];   // 51.2 KB
    __shared__ __align__(16) float part[NT];
    __shared__ __align__(16) float hbuf[R_];
    __shared__ __align__(16) float tmp[R_], tmp2[R_], o3[R_], wbuf[R_], ubuf[R_], bsbuf[R_];
    __shared__ float redw[16][25];
    __shared__ int   idx_o[M2_], idx_s[M2_], tids[L_];
    __shared__ float c0s;

    float* xw   = big;          // [12][512]
    float* xemb = big + 6144;   // [12][64]

    // ================= P1: ids + init =================
    if (tid < M2_) idx_o[tid] = obj[b * M2_ + tid];
    else if (tid >= 128 && tid < 128 + M2_) idx_s[tid - 128] = state[b * M2_ + tid - 128];
    else if (tid >= 256 && tid < 256 + L_) tids[tid - 256] = text[b * L_ + tid - 256];
    else if (tid >= 384 && tid < 512) hbuf[tid - 384] = 0.f;
    __syncthreads();
    if (tid < L_ * E_) xemb[tid] = emb[tids[tid >> 6] * E_ + (tid & 63)];
    __syncthreads();

    // ================= P2: xw[t][col] = b_lstm + x_t @ Wih =================
    // thread = (t-half th, col); 8 weight loads in flight per round
    {
        const int col = tid & 511, th = tid >> 9;
        float bl = b_lstm[col];
        #define DA(i) float a##i = bl;
        X6(DA)
        const float* xe = xemb + (th * 6) * E_;
        #pragma unroll
        for (int e0 = 0; e0 < E_; e0 += 8) {
            float g0 = Wih[(e0 + 0) * 512 + col], g1 = Wih[(e0 + 1) * 512 + col];
            float g2 = Wih[(e0 + 2) * 512 + col], g3 = Wih[(e0 + 3) * 512 + col];
            float g4 = Wih[(e0 + 4) * 512 + col], g5 = Wih[(e0 + 5) * 512 + col];
            float g6 = Wih[(e0 + 6) * 512 + col], g7 = Wih[(e0 + 7) * 512 + col];
            #define FMQ(i) a##i = fmaf(xe[(i) * E_ + ee], gw, a##i);
            #define GRP(jj) { const int ee = e0 + jj; const float gw = g##jj; X6(FMQ) }
            X8(GRP)
            #undef GRP
        }
        #define SA(i) xw[(th * 6 + (i)) * 512 + col] = a##i;
        X6(SA)
    }

    // ================= P4: object MLP -> o3 (no h yet) =================
    const int k = tid & 127, qq = tid >> 7;   // qq 0..7
    {
        float acc = 0.f;
        int c0i = qq * 13, c1i = c0i + 13 < M2_ ? c0i + 13 : M2_;
        #pragma unroll 13
        for (int c = c0i; c < c1i; ++c)
            acc += Wo1[(c * 32 + idx_o[c]) * R_ + k];
        part[qq * R_ + k] = acc;
    }
    __syncthreads();
    if (tid < R_) {
        float a = bo1[tid];
        #pragma unroll
        for (int q8 = 0; q8 < 8; ++q8) a += part[q8 * R_ + tid];
        tmp[tid] = fmaxf(a, 0.f);
    }
    __syncthreads();
    {
        float s0 = 0.f, s1 = 0.f, s2 = 0.f, s3 = 0.f;
        int j0 = qq * 16;
        #pragma unroll
        for (int j = 0; j < 16; j += 4) {
            s0 = fmaf(tmp[j0 + j + 0], Wo2[(j0 + j + 0) * R_ + k], s0);
            s1 = fmaf(tmp[j0 + j + 1], Wo2[(j0 + j + 1) * R_ + k], s1);
            s2 = fmaf(tmp[j0 + j + 2], Wo2[(j0 + j + 2) * R_ + k], s2);
            s3 = fmaf(tmp[j0 + j + 3], Wo2[(j0 + j + 3) * R_ + k], s3);
        }
        part[qq * R_ + k] = (s0 + s1) + (s2 + s3);
    }
    __syncthreads();
    if (tid < R_) {
        float a = bo2[tid];
        #pragma unroll
        for (int q8 = 0; q8 < 8; ++q8) a += part[q8 * R_ + tid];
        tmp2[tid] = fmaxf(a, 0.f);
    }
    __syncthreads();
    {
        float s0 = 0.f, s1 = 0.f, s2 = 0.f, s3 = 0.f;
        int j0 = qq * 16;
        #pragma unroll
        for (int j = 0; j < 16; j += 4) {
            s0 = fmaf(tmp2[j0 + j + 0], Wo3[(j0 + j + 0) * R_ + k], s0);
            s1 = fmaf(tmp2[j0 + j + 1], Wo3[(j0 + j + 1) * R_ + k], s1);
            s2 = fmaf(tmp2[j0 + j + 2], Wo3[(j0 + j + 2) * R_ + k], s2);
            s3 = fmaf(tmp2[j0 + j + 3], Wo3[(j0 + j + 3) * R_ + k], s3);
        }
        part[qq * R_ + k] = (s0 + s1) + (s2 + s3);
    }
    __syncthreads();
    if (tid < R_) {
        float a = bo3[tid];
        #pragma unroll
        for (int q8 = 0; q8 < 8; ++q8) a += part[q8 * R_ + tid];
        o3[tid] = a;                     // object_out (multiply by h later)
    }
    __syncthreads();

    // ================= P6: base_s gather =================
    {
        float acc = 0.f;
        int c0i = qq * 13, c1i = c0i + 13 < M2_ ? c0i + 13 : M2_;
        #pragma unroll 13
        for (int c = c0i; c < c1i; ++c)
            acc += Ws1[(c * 33 + idx_s[c]) * R_ + k];
        part[qq * R_ + k] = acc;
    }
    __syncthreads();
    if (tid < R_) {
        float a = bs1[tid];
        #pragma unroll
        for (int q8 = 0; q8 < 8; ++q8) a += part[q8 * R_ + tid];
        bsbuf[tid] = a;
    }
    __syncthreads();

    // ================= P3: LSTM (thread = (col, h-half); 64 weight VGPRs) =====
    {
        const int col = tid >> 1, half = tid & 1;
        #define DWl(i) float4 wl##i; { const int r = 64 * half + 4 * (i); \
            wl##i.x = Whh[(r + 0) * 512 + col]; wl##i.y = Whh[(r + 1) * 512 + col]; \
            wl##i.z = Whh[(r + 2) * 512 + col]; wl##i.w = Whh[(r + 3) * 512 + col]; } \
            OPQ4(wl##i)
        X16(DWl)
        float cst = 0.f;
        const float4* hb4 = reinterpret_cast<const float4*>(hbuf) + 16 * half;
        for (int t = 0; t < L_; ++t) {
            float s0 = half ? 0.f : xw[t * 512 + col];
            float s1 = 0.f, s2 = 0.f, s3 = 0.f;
            #define FWl(i) { float4 h4 = hb4[i]; \
                s0 = fmaf(h4.x, wl##i.x, s0); s1 = fmaf(h4.y, wl##i.y, s1); \
                s2 = fmaf(h4.z, wl##i.z, s2); s3 = fmaf(h4.w, wl##i.w, s3); }
            X16(FWl)
            float s = (s0 + s1) + (s2 + s3);
            s += __shfl_xor(s, 1, 64);      // combine the two h-halves
            if (!half) part[col] = s;
            __syncthreads();
            if (tid < R_) {
                float gi = part[tid], gf = part[R_ + tid], gg = part[2 * R_ + tid], go = part[3 * R_ + tid];
                cst = sigf(gf) * cst + sigf(gi) * tanhf(gg);
                hbuf[tid] = sigf(go) * tanhf(cst);
            }
            __syncthreads();
        }
    }

    // ================= P8 weights: 16 float4 k-fast from Ws2 (64 VGPRs) =======
    const int q = tid & 7, kg = (tid >> 3) & 31, po = tid >> 8;
    const int jq = q * 16, k4 = kg * 4;
    #define DWs(i) float4 ws##i = *reinterpret_cast<const float4*>(&Ws2[(jq + (i)) * R_ + k4]); OPQ4(ws##i)
    X16(DWs)

    // ================= P5: w = o3*h ; u = Ws3 @ w ; c0 = bs3.w =================
    if (tid < R_) wbuf[tid] = o3[tid] * hbuf[tid];
    __syncthreads();
    {
        float s0 = 0.f, s1 = 0.f, s2 = 0.f, s3 = 0.f;
        int j0 = qq * 16;
        const float4* w3 = reinterpret_cast<const float4*>(&Ws3[k * R_ + j0]);
        #pragma unroll
        for (int jj = 0; jj < 4; ++jj) {
            float4 v = w3[jj];
            s0 = fmaf(v.x, wbuf[j0 + jj * 4 + 0], s0);
            s1 = fmaf(v.y, wbuf[j0 + jj * 4 + 1], s1);
            s2 = fmaf(v.z, wbuf[j0 + jj * 4 + 2], s2);
            s3 = fmaf(v.w, wbuf[j0 + jj * 4 + 3], s3);
        }
        part[qq * R_ + k] = (s0 + s1) + (s2 + s3);
    }
    if (tid >= 960) {
        int j = tid - 960;
        float s = bs3[j] * wbuf[j] + bs3[j + 64] * wbuf[j + 64];
        s += __shfl_down(s, 32, 64);
        s += __shfl_down(s, 16, 64);
        s += __shfl_down(s, 8, 64);
        s += __shfl_down(s, 4, 64);
        s += __shfl_down(s, 2, 64);
        s += __shfl_down(s, 1, 64);
        if (j == 0) c0s = s;
    }
    __syncthreads();
    if (tid < R_) {
        float a = 0.f;
        #pragma unroll
        for (int q8 = 0; q8 < 8; ++q8) a += part[q8 * R_ + tid];
        ubuf[tid] = a;
    }

    // ================= P7: h1[p][j] = relu(bsbuf[j] + Ws1_pos[p][j]) ===========
    for (int i = tid; i < M2_ * R_; i += NT) {
        int p = i >> 7, j = i & 127;
        big[i] = fmaxf(bsbuf[j] + Ws1[(p * 33 + 32) * R_ + j], 0.f);
    }
    __syncthreads();

    // ================= P8: 100 x (128x128), 4 positions in flight ==============
    const float4 uv = *reinterpret_cast<const float4*>(&ubuf[k4]);
    const float4 b2 = *reinterpret_cast<const float4*>(&bs2[k4]);
    const float4* h1b = reinterpret_cast<const float4*>(big);
    #define FP4(i4, WA, WB, WC, WD) { float4 h4 = hrow[i4]; \
        a0 = fmaf(h4.x, WA.x, a0); a1 = fmaf(h4.x, WA.y, a1); a2 = fmaf(h4.x, WA.z, a2); a3 = fmaf(h4.x, WA.w, a3); \
        a0 = fmaf(h4.y, WB.x, a0); a1 = fmaf(h4.y, WB.y, a1); a2 = fmaf(h4.y, WB.z, a2); a3 = fmaf(h4.y, WB.w, a3); \
        a0 = fmaf(h4.z, WC.x, a0); a1 = fmaf(h4.z, WC.y, a1); a2 = fmaf(h4.z, WC.z, a2); a3 = fmaf(h4.z, WC.w, a3); \
        a0 = fmaf(h4.w, WD.x, a0); a1 = fmaf(h4.w, WD.y, a1); a2 = fmaf(h4.w, WD.z, a2); a3 = fmaf(h4.w, WD.w, a3); }
    for (int it = 0; it < 25; ++it) {
        int pl = it * 4 + po;
        const float4* hrow = h1b + pl * 32 + q * 4;   // j = q*16 .. q*16+15
        float a0 = 0.f, a1 = 0.f, a2 = 0.f, a3 = 0.f;
        FP4(0, ws0,  ws1,  ws2,  ws3)
        FP4(1, ws4,  ws5,  ws6,  ws7)
        FP4(2, ws8,  ws9,  ws10, ws11)
        FP4(3, ws12, ws13, ws14, ws15)
        // j-reduction over q (lane bits 0..2)
        a0 += __shfl_xor(a0, 1, 64); a0 += __shfl_xor(a0, 2, 64); a0 += __shfl_xor(a0, 4, 64);
        a1 += __shfl_xor(a1, 1, 64); a1 += __shfl_xor(a1, 2, 64); a1 += __shfl_xor(a1, 4, 64);
        a2 += __shfl_xor(a2, 1, 64); a2 += __shfl_xor(a2, 2, 64); a2 += __shfl_xor(a2, 4, 64);
        a3 += __shfl_xor(a3, 1, 64); a3 += __shfl_xor(a3, 2, 64); a3 += __shfl_xor(a3, 4, 64);
        float val = fmaxf(a0 + b2.x, 0.f) * uv.x + fmaxf(a1 + b2.y, 0.f) * uv.y
                  + fmaxf(a2 + b2.z, 0.f) * uv.z + fmaxf(a3 + b2.w, 0.f) * uv.w;
        // k-reduction over kg low bits (lane bits 3..5)
        val += __shfl_xor(val, 8, 64);
        val += __shfl_xor(val, 16, 64);
        val += __shfl_xor(val, 32, 64);
        if ((tid & 63) == 0) redw[tid >> 6][it] = val;   // wave = po*4 + kseg
    }
    __syncthreads();

    // ================= P9: combine 4 k-segment waves per position ==============
    if (tid < M2_) {
        int it = tid >> 2, po2 = tid & 3;
        out[b * M2_ + tid] = c0s + redw[po2 * 4 + 0][it] + redw[po2 * 4 + 1][it]
                                 + redw[po2 * 4 + 2][it] + redw[po2 * 4 + 3][it];
    }
}

extern "C" void kernel_launch(void* const* d_in, const int* in_sizes, int n_in,
                              void* d_out, int out_size, void* d_ws, size_t ws_size,
                              hipStream_t stream) {
    const int*   state  = (const int*)d_in[0];
    const int*   obj    = (const int*)d_in[1];
    const int*   text   = (const int*)d_in[2];
    const float* Ws1    = (const float*)d_in[3];
    const float* bs1    = (const float*)d_in[4];
    const float* Ws2    = (const float*)d_in[5];
    const float* bs2    = (const float*)d_in[6];
    const float* Ws3    = (const float*)d_in[7];
    const float* bs3    = (const float*)d_in[8];
    const float* Wo1    = (const float*)d_in[9];
    const float* bo1    = (const float*)d_in[10];
    const float* Wo2    = (const float*)d_in[11];
    const float* bo2    = (const float*)d_in[12];
    const float* Wo3    = (const float*)d_in[13];
    const float* bo3    = (const float*)d_in[14];
    const float* emb    = (const float*)d_in[15];
    const float* Wih    = (const float*)d_in[16];
    const float* Whh    = (const float*)d_in[17];
    const float* b_lstm = (const float*)d_in[18];
    float* out = (float*)d_out;

    hipLaunchKernelGGL(uvfa_kernel, dim3(B_), dim3(NT), 0, stream,
                       state, obj, text, Ws1, bs1, Ws2, bs2, Ws3, bs3,
                       Wo1, bo1, Wo2, bo2, Wo3, bo3, emb, Wih, Whh, b_lstm, out);
}

// Round 7
// 52.398 us; speedup vs baseline: 1.4801x; 1.3513x over previous
//
#include <hip/hip_runtime.h>

// UVFA_text: B=256, M2=100, SV=OV=32, R=128, L=12, V=1000, E=64
// out[b,p] = sum_k relu(h2[p,k]+bs2[k]) * u[k] + bs3.w
//   h2[p,k] = relu(base_s + Ws1_pos[p]) @ Ws2[:,k]
//   base_s  = bs1 + sum_c Ws1[c*33+state[b,c]]
//   w = obj_mlp(b) * lstm_h(b);  u[k] = Ws3[k,:] . w
// Strategy (r7): weights for the two inner loops live in LDS as f16 pairs,
// consumed via v_dot2_f32_f16 (f32 accumulate). No register-resident weight
// slices -> nothing to spill. 256 blocks x 512 threads, 1 block/CU (138KB LDS).

#define B_   256
#define M2_  100
#define R_   128
#define L_   12
#define E_   64
#define NT   512

typedef _Float16 half2v __attribute__((ext_vector_type(2)));

__device__ __forceinline__ float sigf(float x) { return 1.f / (1.f + expf(-x)); }

__device__ __forceinline__ uint pk16(float a, float b) {
    half2v h; h.x = (_Float16)a; h.y = (_Float16)b;
    return __builtin_bit_cast(uint, h);
}

__device__ __forceinline__ float fdot2u(uint a, uint b, float c) {
    half2v ha = __builtin_bit_cast(half2v, a);
    half2v hb = __builtin_bit_cast(half2v, b);
#if __has_builtin(__builtin_amdgcn_fdot2)
    return __builtin_amdgcn_fdot2(ha, hb, c, false);
#else
    return c + (float)ha.x * (float)hb.x + (float)ha.y * (float)hb.y;
#endif
}

#define X12(OP) OP(0) OP(1) OP(2) OP(3) OP(4) OP(5) OP(6) OP(7) OP(8) OP(9) OP(10) OP(11)

__global__ __launch_bounds__(NT) void uvfa_kernel(
    const int* __restrict__ state, const int* __restrict__ obj, const int* __restrict__ text,
    const float* __restrict__ Ws1, const float* __restrict__ bs1,
    const float* __restrict__ Ws2, const float* __restrict__ bs2,
    const float* __restrict__ Ws3, const float* __restrict__ bs3,
    const float* __restrict__ Wo1, const float* __restrict__ bo1,
    const float* __restrict__ Wo2, const float* __restrict__ bo2,
    const float* __restrict__ Wo3, const float* __restrict__ bo3,
    const float* __restrict__ emb, const float* __restrict__ Wih,
    const float* __restrict__ Whh, const float* __restrict__ b_lstm,
    float* __restrict__ out)
{
    const int b   = blockIdx.x;
    const int tid = threadIdx.x;

    // U (128 KiB union):
    //   phase P1/P2 : xemb[12][64] f32 (first 3 KiB)
    //   phase LSTM  : WhhP[64][512] u32 = f16x2 pairs of Whh rows (2jp,2jp+1)
    //   phase P8    : Ws2P[64][128] u32 (0..8191) + h1P[64][104] u32 (8192..)
    __shared__ __align__(16) uint  U[32768];
    __shared__ __align__(16) float part[NT];
    __shared__ __align__(16) float hbuf[R_];
    __shared__ uint  hpair[R_ / 2];
    __shared__ __align__(16) float tmp[R_], tmp2[R_], wbuf[R_], ubuf[R_], bsbuf[R_];
    __shared__ int   idx_o[M2_], idx_s[M2_], tids[L_];
    __shared__ float c0s;

    float* xemb = (float*)U;

    // ---------------- P1: ids + init ----------------
    if (tid < M2_) idx_o[tid] = obj[b * M2_ + tid];
    else if (tid >= 128 && tid < 128 + M2_) idx_s[tid - 128] = state[b * M2_ + tid - 128];
    else if (tid >= 256 && tid < 256 + L_) tids[tid - 256] = text[b * L_ + tid - 256];
    else if (tid >= 384 && tid < 448) hpair[tid - 384] = 0u;
    __syncthreads();
    for (int i = tid; i < L_ * E_; i += NT)
        xemb[i] = emb[tids[i >> 6] * E_ + (i & 63)];
    __syncthreads();

    // ---------------- P2: xw[t] (12 registers), thread = gate column ----------
    float bl = b_lstm[tid];
    #define DA(i) float a##i = bl;
    X12(DA)
    #pragma unroll 8
    for (int e = 0; e < E_; ++e) {
        float we = Wih[e * 512 + tid];
        #define FA(i) a##i = fmaf(xemb[(i) * E_ + e], we, a##i);
        X12(FA)
    }
    __syncthreads();   // xemb dead; U free

    // ---------------- Whh -> LDS as f16 pairs (256KB -> 128KB, read ONCE) -----
    #pragma unroll 4
    for (int idx = tid; idx < 64 * 512; idx += NT) {
        int jp = idx >> 9, c = idx & 511;
        U[idx] = pk16(Whh[(2 * jp) * 512 + c], Whh[(2 * jp + 1) * 512 + c]);
    }
    __syncthreads();

    // ---------------- LSTM: 12 steps, gates via fdot2 from LDS ----------------
    float cst = 0.f;
    #define LSTM_STEP(t) { \
        float g0 = a##t, g1 = 0.f, g2 = 0.f, g3 = 0.f; \
        _Pragma("unroll 8") \
        for (int jp = 0; jp < 64; jp += 4) { \
            uint h0 = hpair[jp], h1v = hpair[jp + 1], h2v = hpair[jp + 2], h3v = hpair[jp + 3]; \
            g0 = fdot2u(U[(jp + 0) * 512 + tid], h0, g0); \
            g1 = fdot2u(U[(jp + 1) * 512 + tid], h1v, g1); \
            g2 = fdot2u(U[(jp + 2) * 512 + tid], h2v, g2); \
            g3 = fdot2u(U[(jp + 3) * 512 + tid], h3v, g3); \
        } \
        part[tid] = (g0 + g1) + (g2 + g3); \
        __syncthreads(); \
        if (tid < R_) { \
            float gi = part[tid], gf = part[R_ + tid], gg = part[2 * R_ + tid], go = part[3 * R_ + tid]; \
            cst = sigf(gf) * cst + sigf(gi) * tanhf(gg); \
            float hn = sigf(go) * tanhf(cst); \
            hbuf[tid] = hn; \
            float hs = __shfl_down(hn, 1, 64); \
            if ((tid & 1) == 0) hpair[tid >> 1] = pk16(hn, hs); \
        } \
        __syncthreads(); }
    X12(LSTM_STEP)

    // ---------------- P4: object MLP (fp32, read-once weights) ----------------
    const int k = tid & 127, qq = tid >> 7;   // qq 0..3
    {
        float acc = 0.f;
        #pragma unroll 5
        for (int c = qq * 25; c < qq * 25 + 25; ++c)
            acc += Wo1[(c * 32 + idx_o[c]) * R_ + k];
        part[qq * R_ + k] = acc;
    }
    __syncthreads();
    if (tid < R_)
        tmp[tid] = fmaxf(bo1[tid] + part[tid] + part[R_ + tid] + part[2 * R_ + tid] + part[3 * R_ + tid], 0.f);
    __syncthreads();
    {
        float s0 = 0.f, s1 = 0.f, s2 = 0.f, s3 = 0.f;
        int j0 = qq * 32;
        #pragma unroll
        for (int j = 0; j < 32; j += 4) {
            s0 = fmaf(tmp[j0 + j + 0], Wo2[(j0 + j + 0) * R_ + k], s0);
            s1 = fmaf(tmp[j0 + j + 1], Wo2[(j0 + j + 1) * R_ + k], s1);
            s2 = fmaf(tmp[j0 + j + 2], Wo2[(j0 + j + 2) * R_ + k], s2);
            s3 = fmaf(tmp[j0 + j + 3], Wo2[(j0 + j + 3) * R_ + k], s3);
        }
        part[qq * R_ + k] = (s0 + s1) + (s2 + s3);
    }
    __syncthreads();
    if (tid < R_)
        tmp2[tid] = fmaxf(bo2[tid] + part[tid] + part[R_ + tid] + part[2 * R_ + tid] + part[3 * R_ + tid], 0.f);
    __syncthreads();
    {
        float s0 = 0.f, s1 = 0.f, s2 = 0.f, s3 = 0.f;
        int j0 = qq * 32;
        #pragma unroll
        for (int j = 0; j < 32; j += 4) {
            s0 = fmaf(tmp2[j0 + j + 0], Wo3[(j0 + j + 0) * R_ + k], s0);
            s1 = fmaf(tmp2[j0 + j + 1], Wo3[(j0 + j + 1) * R_ + k], s1);
            s2 = fmaf(tmp2[j0 + j + 2], Wo3[(j0 + j + 2) * R_ + k], s2);
            s3 = fmaf(tmp2[j0 + j + 3], Wo3[(j0 + j + 3) * R_ + k], s3);
        }
        part[qq * R_ + k] = (s0 + s1) + (s2 + s3);
    }
    __syncthreads();
    if (tid < R_)
        wbuf[tid] = (bo3[tid] + part[tid] + part[R_ + tid] + part[2 * R_ + tid] + part[3 * R_ + tid]) * hbuf[tid];
    __syncthreads();

    // ---------------- P5: u = Ws3 @ w ; c0 = bs3 . w ----------------
    {
        float s0 = 0.f, s1 = 0.f, s2 = 0.f, s3 = 0.f;
        const float4* w4 = reinterpret_cast<const float4*>(&Ws3[k * R_ + qq * 32]);
        #pragma unroll
        for (int jj = 0; jj < 8; ++jj) {
            float4 v = w4[jj];
            int j0 = qq * 32 + jj * 4;
            s0 = fmaf(v.x, wbuf[j0 + 0], s0);
            s1 = fmaf(v.y, wbuf[j0 + 1], s1);
            s2 = fmaf(v.z, wbuf[j0 + 2], s2);
            s3 = fmaf(v.w, wbuf[j0 + 3], s3);
        }
        part[qq * R_ + k] = (s0 + s1) + (s2 + s3);
    }
    if (tid >= 448) {
        int j = tid - 448;
        float s = bs3[j] * wbuf[j] + bs3[j + 64] * wbuf[j + 64];
        s += __shfl_down(s, 32, 64);
        s += __shfl_down(s, 16, 64);
        s += __shfl_down(s, 8, 64);
        s += __shfl_down(s, 4, 64);
        s += __shfl_down(s, 2, 64);
        s += __shfl_down(s, 1, 64);
        if (j == 0) c0s = s;
    }
    __syncthreads();
    if (tid < R_)
        ubuf[tid] = part[tid] + part[R_ + tid] + part[2 * R_ + tid] + part[3 * R_ + tid];

    // ---------------- P6: base_s gather ----------------
    {
        float acc = 0.f;
        #pragma unroll 5
        for (int c = qq * 25; c < qq * 25 + 25; ++c)
            acc += Ws1[(c * 33 + idx_s[c]) * R_ + k];
        part[qq * R_ + k] = acc;
    }
    __syncthreads();
    if (tid < R_)
        bsbuf[tid] = bs1[tid] + part[tid] + part[R_ + tid] + part[2 * R_ + tid] + part[3 * R_ + tid];
    __syncthreads();   // bsbuf + ubuf ready; WhhP dead

    // ---------------- stage Ws2P (f16 pairs) + h1P (f16 pairs) into U ---------
    #pragma unroll
    for (int idx = tid; idx < 64 * 128; idx += NT) {   // 16 iters
        int jp = idx >> 7, kk = idx & 127;
        U[idx] = pk16(Ws2[(2 * jp) * R_ + kk], Ws2[(2 * jp + 1) * R_ + kk]);
    }
    #pragma unroll 5
    for (int pass = 0; pass < 25; ++pass) {            // h1[p][j], packed along j
        int idx = pass * NT + tid;                     // < 12800
        int j = idx & 127, p = idx >> 7;
        float v = fmaxf(bsbuf[j] + Ws1[(p * 33 + 32) * R_ + j], 0.f);
        float v2 = __shfl_down(v, 1, 64);
        if ((j & 1) == 0) U[8192 + (j >> 1) * 104 + p] = pk16(v, v2);
    }
    __syncthreads();

    // ---------------- P8: 100 x (128x128) via dot2; thread = 4p x 8k ----------
    if (tid < 400) {
        const int pq = tid >> 4, ko = tid & 15;
        const uint* Wsp = U + 8 * ko;
        const uint* Hp  = U + 8192 + 4 * pq;
        float4 uA = *(const float4*)&ubuf[8 * ko];
        float4 uB = *(const float4*)&ubuf[8 * ko + 4];
        float4 bA = *(const float4*)&bs2[8 * ko];
        float4 bB = *(const float4*)&bs2[8 * ko + 4];
        float acc[4][8];
        #pragma unroll
        for (int pi = 0; pi < 4; ++pi)
            #pragma unroll
            for (int r = 0; r < 8; ++r) acc[pi][r] = 0.f;
        #pragma unroll 2
        for (int jp = 0; jp < 64; ++jp) {
            uint4 hq = *(const uint4*)(Hp  + jp * 104);
            uint4 w0 = *(const uint4*)(Wsp + jp * 128);
            uint4 w1 = *(const uint4*)(Wsp + jp * 128 + 4);
            #pragma unroll
            for (int pi = 0; pi < 4; ++pi) {
                uint hh = pi == 0 ? hq.x : pi == 1 ? hq.y : pi == 2 ? hq.z : hq.w;
                acc[pi][0] = fdot2u(hh, w0.x, acc[pi][0]);
                acc[pi][1] = fdot2u(hh, w0.y, acc[pi][1]);
                acc[pi][2] = fdot2u(hh, w0.z, acc[pi][2]);
                acc[pi][3] = fdot2u(hh, w0.w, acc[pi][3]);
                acc[pi][4] = fdot2u(hh, w1.x, acc[pi][4]);
                acc[pi][5] = fdot2u(hh, w1.y, acc[pi][5]);
                acc[pi][6] = fdot2u(hh, w1.z, acc[pi][6]);
                acc[pi][7] = fdot2u(hh, w1.w, acc[pi][7]);
            }
        }
        #pragma unroll
        for (int pi = 0; pi < 4; ++pi) {
            float s = fmaxf(acc[pi][0] + bA.x, 0.f) * uA.x + fmaxf(acc[pi][1] + bA.y, 0.f) * uA.y
                    + fmaxf(acc[pi][2] + bA.z, 0.f) * uA.z + fmaxf(acc[pi][3] + bA.w, 0.f) * uA.w
                    + fmaxf(acc[pi][4] + bB.x, 0.f) * uB.x + fmaxf(acc[pi][5] + bB.y, 0.f) * uB.y
                    + fmaxf(acc[pi][6] + bB.z, 0.f) * uB.z + fmaxf(acc[pi][7] + bB.w, 0.f) * uB.w;
            // k-reduction over the 16 ko lanes (lane bits 0..3)
            s += __shfl_xor(s, 1, 64);
            s += __shfl_xor(s, 2, 64);
            s += __shfl_xor(s, 4, 64);
            s += __shfl_xor(s, 8, 64);
            if (ko == 0) out[b * M2_ + 4 * pq + pi] = s + c0s;
        }
    }
}

extern "C" void kernel_launch(void* const* d_in, const int* in_sizes, int n_in,
                              void* d_out, int out_size, void* d_ws, size_t ws_size,
                              hipStream_t stream) {
    const int*   state  = (const int*)d_in[0];
    const int*   obj    = (const int*)d_in[1];
    const int*   text   = (const int*)d_in[2];
    const float* Ws1    = (const float*)d_in[3];
    const float* bs1    = (const float*)d_in[4];
    const float* Ws2    = (const float*)d_in[5];
    const float* bs2    = (const float*)d_in[6];
    const float* Ws3    = (const float*)d_in[7];
    const float* bs3    = (const float*)d_in[8];
    const float* Wo1    = (const float*)d_in[9];
    const float* bo1    = (const float*)d_in[10];
    const float* Wo2    = (const float*)d_in[11];
    const float* bo2    = (const float*)d_in[12];
    const float* Wo3    = (const float*)d_in[13];
    const float* bo3    = (const float*)d_in[14];
    const float* emb    = (const float*)d_in[15];
    const float* Wih    = (const float*)d_in[16];
    const float* Whh    = (const float*)d_in[17];
    const float* b_lstm = (const float*)d_in[18];
    float* out = (float*)d_out;

    hipLaunchKernelGGL(uvfa_kernel, dim3(B_), dim3(NT), 0, stream,
                       state, obj, text, Ws1, bs1, Ws2, bs2, Ws3, bs3,
                       Wo1, bo1, Wo2, bo2, Wo3, bo3, emb, Wih, Whh, b_lstm, out);
}

// Round 8
// 46.756 us; speedup vs baseline: 1.6587x; 1.1207x over previous
//
#include <hip/hip_runtime.h>

// UVFA_text: B=256, M2=100, SV=OV=32, R=128, L=12, V=1000, E=64
// out[b,p] = sum_k relu(h2[p,k]+bs2[k]) * u[k] + bs3.w
//   h2[p,k] = relu(base_s + Ws1_pos[p]) @ Ws2[:,k]
//   w = obj_mlp(b) * lstm_h(b);  u[k] = Ws3[k,:] . w
// r8: LSTM gates via MFMA with Whh held in A-fragments (32 VGPR/thread,
// never re-read); 1024 threads (16 waves); P8 stays r7's LDS-f16 dot2.

#define B_   256
#define M2_  100
#define R_   128
#define L_   12
#define E_   64
#define NT   1024

typedef _Float16 half2v __attribute__((ext_vector_type(2)));
typedef _Float16 f16x8  __attribute__((ext_vector_type(8)));
typedef float    f32x4  __attribute__((ext_vector_type(4)));

__device__ __forceinline__ float sigf(float x) { return 1.f / (1.f + expf(-x)); }

__device__ __forceinline__ uint pk16(float a, float b) {
    half2v h; h.x = (_Float16)a; h.y = (_Float16)b;
    return __builtin_bit_cast(uint, h);
}

__device__ __forceinline__ float fdot2u(uint a, uint b, float c) {
    half2v ha = __builtin_bit_cast(half2v, a);
    half2v hb = __builtin_bit_cast(half2v, b);
#if __has_builtin(__builtin_amdgcn_fdot2)
    return __builtin_amdgcn_fdot2(ha, hb, c, false);
#else
    return c + (float)ha.x * (float)hb.x + (float)ha.y * (float)hb.y;
#endif
}

#define X6(OP) OP(0) OP(1) OP(2) OP(3) OP(4) OP(5)

__global__ __launch_bounds__(NT, 4) void uvfa_kernel(
    const int* __restrict__ state, const int* __restrict__ obj, const int* __restrict__ text,
    const float* __restrict__ Ws1, const float* __restrict__ bs1,
    const float* __restrict__ Ws2, const float* __restrict__ bs2,
    const float* __restrict__ Ws3, const float* __restrict__ bs3,
    const float* __restrict__ Wo1, const float* __restrict__ bo1,
    const float* __restrict__ Wo2, const float* __restrict__ bo2,
    const float* __restrict__ Wo3, const float* __restrict__ bo3,
    const float* __restrict__ emb, const float* __restrict__ Wih,
    const float* __restrict__ Whh, const float* __restrict__ b_lstm,
    float* __restrict__ out)
{
    const int b   = blockIdx.x;
    const int tid = threadIdx.x;

    // U (58 KiB union): phase A = xw[12][512] f32 (0..6143) + xemb[768] f32;
    //                   phase B = Ws2P[64][128] u32 (0..8191) + h1P[64][104] u32 (8192..14847)
    __shared__ __align__(16) uint  U[14848];
    __shared__ __align__(16) float part[NT];
    __shared__ __align__(16) float hbuf[R_];
    __shared__ __align__(16) uint  hpair[R_ / 2];
    __shared__ __align__(16) float tmp[R_], tmp2[R_], wbuf[R_], ubuf[R_], bsbuf[R_];
    __shared__ int   idx_o[M2_], idx_s[M2_], tids[L_];
    __shared__ float c0s;

    float* xw   = (float*)U;            // [12][512]
    float* xemb = (float*)(U + 6144);   // [12][64]

    const int lane = tid & 63;
    const int wv   = tid >> 6;          // 0..15
    const int m16  = lane & 15;         // A row within tile / D col n
    const int kg   = lane >> 4;         // 0..3 (k-group)

    // ---------- A-fragments: Whh^T tiles held in registers for the whole LSTM ----------
    // tile T = 2*wv+tt covers gate cols T*16..T*16+15; A[m][k] = Whh[k][T*16+m]
    f16x8 af[2][4];
    #pragma unroll
    for (int tt = 0; tt < 2; ++tt) {
        int col = (2 * wv + tt) * 16 + m16;
        #pragma unroll
        for (int s = 0; s < 4; ++s) {
            int kb = s * 32 + kg * 8;
            #pragma unroll
            for (int e = 0; e < 8; ++e)
                af[tt][s][e] = (_Float16)Whh[(kb + e) * 512 + col];
        }
    }

    // ---------- P1: ids + init ----------
    if (tid < M2_) idx_o[tid] = obj[b * M2_ + tid];
    else if (tid >= 128 && tid < 128 + M2_) idx_s[tid - 128] = state[b * M2_ + tid - 128];
    else if (tid >= 256 && tid < 256 + L_) tids[tid - 256] = text[b * L_ + tid - 256];
    else if (tid >= 384 && tid < 448) hpair[tid - 384] = 0u;
    __syncthreads();
    if (tid < L_ * E_) xemb[tid] = emb[tids[tid >> 6] * E_ + (tid & 63)];
    __syncthreads();

    // ---------- P2: xw[t][col] = b_lstm[col] + x_t @ Wih (thread = (t-half, col)) ----------
    {
        const int col = tid & 511, th = tid >> 9;
        float bl = b_lstm[col];
        #define DA(i) float a##i = bl;
        X6(DA)
        const float* xe = xemb + (th * 6) * E_;
        #pragma unroll 8
        for (int e = 0; e < E_; ++e) {
            float we = Wih[e * 512 + col];
            #define FA(i) a##i = fmaf(xe[(i) * E_ + e], we, a##i);
            X6(FA)
        }
        #define SA(i) xw[(th * 6 + (i)) * 512 + col] = a##i;
        X6(SA)
    }
    __syncthreads();   // xw + hpair ready

    // ---------- LSTM: 12 steps, gates = MFMA(A=Whh^T, B=h in col 0, C=xw) ----------
    float cst = 0.f;
    for (int t = 0; t < L_; ++t) {
        f16x8 bf[4];
        #pragma unroll
        for (int s = 0; s < 4; ++s) {
            uint4 hb = *(const uint4*)&hpair[s * 16 + kg * 4];   // uniform per kg
            bf[s] = __builtin_bit_cast(f16x8, hb);
        }
        #pragma unroll
        for (int tt = 0; tt < 2; ++tt) {
            int colb = (2 * wv + tt) * 16 + kg * 4;
            f32x4 acc = *(const f32x4*)&xw[t * 512 + colb];      // C-init = xw_t
            #pragma unroll
            for (int s = 0; s < 4; ++s)
                acc = __builtin_amdgcn_mfma_f32_16x16x32_f16(af[tt][s], bf[s], acc, 0, 0, 0);
            if (m16 == 0) {                                      // D col 0 = gates
                part[colb + 0] = acc[0];
                part[colb + 1] = acc[1];
                part[colb + 2] = acc[2];
                part[colb + 3] = acc[3];
            }
        }
        __syncthreads();
        if (tid < R_) {
            float gi = part[tid], gf = part[R_ + tid], gg = part[2 * R_ + tid], go = part[3 * R_ + tid];
            cst = sigf(gf) * cst + sigf(gi) * tanhf(gg);
            float hn = sigf(go) * tanhf(cst);
            hbuf[tid] = hn;
            float hs = __shfl_down(hn, 1, 64);
            if (!(tid & 1)) hpair[tid >> 1] = pk16(hn, hs);
        }
        __syncthreads();
    }

    // ---------- stage Ws2P into U[0..8191] (xw dead) ----------
    #pragma unroll
    for (int idx = tid; idx < 64 * 128; idx += NT) {   // 8 iters
        int jp = idx >> 7, kk = idx & 127;
        U[idx] = pk16(Ws2[(2 * jp) * R_ + kk], Ws2[(2 * jp + 1) * R_ + kk]);
    }

    // ---------- P4: object MLP (8-way split) ----------
    const int k = tid & 127, qq = tid >> 7;   // qq 0..7
    {
        float acc = 0.f;
        int c0i = qq * 13, c1i = c0i + 13 < M2_ ? c0i + 13 : M2_;
        for (int c = c0i; c < c1i; ++c)
            acc += Wo1[(c * 32 + idx_o[c]) * R_ + k];
        part[qq * R_ + k] = acc;
    }
    __syncthreads();
    if (tid < R_) {
        float a = bo1[tid];
        #pragma unroll
        for (int q8 = 0; q8 < 8; ++q8) a += part[q8 * R_ + tid];
        tmp[tid] = fmaxf(a, 0.f);
    }
    __syncthreads();
    {
        float s0 = 0.f, s1 = 0.f, s2 = 0.f, s3 = 0.f;
        int j0 = qq * 16;
        #pragma unroll
        for (int j = 0; j < 16; j += 4) {
            s0 = fmaf(tmp[j0 + j + 0], Wo2[(j0 + j + 0) * R_ + k], s0);
            s1 = fmaf(tmp[j0 + j + 1], Wo2[(j0 + j + 1) * R_ + k], s1);
            s2 = fmaf(tmp[j0 + j + 2], Wo2[(j0 + j + 2) * R_ + k], s2);
            s3 = fmaf(tmp[j0 + j + 3], Wo2[(j0 + j + 3) * R_ + k], s3);
        }
        part[qq * R_ + k] = (s0 + s1) + (s2 + s3);
    }
    __syncthreads();
    if (tid < R_) {
        float a = bo2[tid];
        #pragma unroll
        for (int q8 = 0; q8 < 8; ++q8) a += part[q8 * R_ + tid];
        tmp2[tid] = fmaxf(a, 0.f);
    }
    __syncthreads();
    {
        float s0 = 0.f, s1 = 0.f, s2 = 0.f, s3 = 0.f;
        int j0 = qq * 16;
        #pragma unroll
        for (int j = 0; j < 16; j += 4) {
            s0 = fmaf(tmp2[j0 + j + 0], Wo3[(j0 + j + 0) * R_ + k], s0);
            s1 = fmaf(tmp2[j0 + j + 1], Wo3[(j0 + j + 1) * R_ + k], s1);
            s2 = fmaf(tmp2[j0 + j + 2], Wo3[(j0 + j + 2) * R_ + k], s2);
            s3 = fmaf(tmp2[j0 + j + 3], Wo3[(j0 + j + 3) * R_ + k], s3);
        }
        part[qq * R_ + k] = (s0 + s1) + (s2 + s3);
    }
    __syncthreads();
    if (tid < R_) {
        float a = bo3[tid];
        #pragma unroll
        for (int q8 = 0; q8 < 8; ++q8) a += part[q8 * R_ + tid];
        wbuf[tid] = a * hbuf[tid];
    }
    __syncthreads();

    // ---------- P5: u = Ws3 @ w ; c0 = bs3 . w ----------
    {
        float s0 = 0.f, s1 = 0.f, s2 = 0.f, s3 = 0.f;
        int j0 = qq * 16;
        const float4* w3 = reinterpret_cast<const float4*>(&Ws3[k * R_ + j0]);
        #pragma unroll
        for (int jj = 0; jj < 4; ++jj) {
            float4 v = w3[jj];
            s0 = fmaf(v.x, wbuf[j0 + jj * 4 + 0], s0);
            s1 = fmaf(v.y, wbuf[j0 + jj * 4 + 1], s1);
            s2 = fmaf(v.z, wbuf[j0 + jj * 4 + 2], s2);
            s3 = fmaf(v.w, wbuf[j0 + jj * 4 + 3], s3);
        }
        part[qq * R_ + k] = (s0 + s1) + (s2 + s3);
    }
    if (tid >= 960) {
        int j = tid - 960;
        float s = bs3[j] * wbuf[j] + bs3[j + 64] * wbuf[j + 64];
        s += __shfl_down(s, 32, 64);
        s += __shfl_down(s, 16, 64);
        s += __shfl_down(s, 8, 64);
        s += __shfl_down(s, 4, 64);
        s += __shfl_down(s, 2, 64);
        s += __shfl_down(s, 1, 64);
        if (j == 0) c0s = s;
    }
    __syncthreads();
    if (tid < R_) {
        float a = 0.f;
        #pragma unroll
        for (int q8 = 0; q8 < 8; ++q8) a += part[q8 * R_ + tid];
        ubuf[tid] = a;
    }
    __syncthreads();   // part free for P6

    // ---------- P6: base_s gather ----------
    {
        float acc = 0.f;
        int c0i = qq * 13, c1i = c0i + 13 < M2_ ? c0i + 13 : M2_;
        for (int c = c0i; c < c1i; ++c)
            acc += Ws1[(c * 33 + idx_s[c]) * R_ + k];
        part[qq * R_ + k] = acc;
    }
    __syncthreads();
    if (tid < R_) {
        float a = bs1[tid];
        #pragma unroll
        for (int q8 = 0; q8 < 8; ++q8) a += part[q8 * R_ + tid];
        bsbuf[tid] = a;
    }
    __syncthreads();

    // ---------- stage h1P (f16 pairs along j) into U[8192..] ----------
    #pragma unroll 4
    for (int pass = 0; pass < 13; ++pass) {
        int idx = pass * NT + tid;
        if (idx < M2_ * R_) {
            int j = idx & 127, p = idx >> 7;
            float v = fmaxf(bsbuf[j] + Ws1[(p * 33 + 32) * R_ + j], 0.f);
            float v2 = __shfl_down(v, 1, 64);
            if (!(j & 1)) U[8192 + (j >> 1) * 104 + p] = pk16(v, v2);
        }
    }
    __syncthreads();

    // ---------- P8: 100 x (128x128) via dot2; thread = 4p x 8k (r7) ----------
    if (tid < 400) {
        const int pq = tid >> 4, ko = tid & 15;
        const uint* Wsp = U + 8 * ko;
        const uint* Hp  = U + 8192 + 4 * pq;
        float4 uA = *(const float4*)&ubuf[8 * ko];
        float4 uB = *(const float4*)&ubuf[8 * ko + 4];
        float4 bA = *(const float4*)&bs2[8 * ko];
        float4 bB = *(const float4*)&bs2[8 * ko + 4];
        float acc[4][8];
        #pragma unroll
        for (int pi = 0; pi < 4; ++pi)
            #pragma unroll
            for (int r = 0; r < 8; ++r) acc[pi][r] = 0.f;
        #pragma unroll 2
        for (int jp = 0; jp < 64; ++jp) {
            uint4 hq = *(const uint4*)(Hp  + jp * 104);
            uint4 w0 = *(const uint4*)(Wsp + jp * 128);
            uint4 w1 = *(const uint4*)(Wsp + jp * 128 + 4);
            #pragma unroll
            for (int pi = 0; pi < 4; ++pi) {
                uint hh = pi == 0 ? hq.x : pi == 1 ? hq.y : pi == 2 ? hq.z : hq.w;
                acc[pi][0] = fdot2u(hh, w0.x, acc[pi][0]);
                acc[pi][1] = fdot2u(hh, w0.y, acc[pi][1]);
                acc[pi][2] = fdot2u(hh, w0.z, acc[pi][2]);
                acc[pi][3] = fdot2u(hh, w0.w, acc[pi][3]);
                acc[pi][4] = fdot2u(hh, w1.x, acc[pi][4]);
                acc[pi][5] = fdot2u(hh, w1.y, acc[pi][5]);
                acc[pi][6] = fdot2u(hh, w1.z, acc[pi][6]);
                acc[pi][7] = fdot2u(hh, w1.w, acc[pi][7]);
            }
        }
        #pragma unroll
        for (int pi = 0; pi < 4; ++pi) {
            float s = fmaxf(acc[pi][0] + bA.x, 0.f) * uA.x + fmaxf(acc[pi][1] + bA.y, 0.f) * uA.y
                    + fmaxf(acc[pi][2] + bA.z, 0.f) * uA.z + fmaxf(acc[pi][3] + bA.w, 0.f) * uA.w
                    + fmaxf(acc[pi][4] + bB.x, 0.f) * uB.x + fmaxf(acc[pi][5] + bB.y, 0.f) * uB.y
                    + fmaxf(acc[pi][6] + bB.z, 0.f) * uB.z + fmaxf(acc[pi][7] + bB.w, 0.f) * uB.w;
            s += __shfl_xor(s, 1, 64);
            s += __shfl_xor(s, 2, 64);
            s += __shfl_xor(s, 4, 64);
            s += __shfl_xor(s, 8, 64);
            if (ko == 0) out[b * M2_ + 4 * pq + pi] = s + c0s;
        }
    }
}

extern "C" void kernel_launch(void* const* d_in, const int* in_sizes, int n_in,
                              void* d_out, int out_size, void* d_ws, size_t ws_size,
                              hipStream_t stream) {
    const int*   state  = (const int*)d_in[0];
    const int*   obj    = (const int*)d_in[1];
    const int*   text   = (const int*)d_in[2];
    const float* Ws1    = (const float*)d_in[3];
    const float* bs1    = (const float*)d_in[4];
    const float* Ws2    = (const float*)d_in[5];
    const float* bs2    = (const float*)d_in[6];
    const float* Ws3    = (const float*)d_in[7];
    const float* bs3    = (const float*)d_in[8];
    const float* Wo1    = (const float*)d_in[9];
    const float* bo1    = (const float*)d_in[10];
    const float* Wo2    = (const float*)d_in[11];
    const float* bo2    = (const float*)d_in[12];
    const float* Wo3    = (const float*)d_in[13];
    const float* bo3    = (const float*)d_in[14];
    const float* emb    = (const float*)d_in[15];
    const float* Wih    = (const float*)d_in[16];
    const float* Whh    = (const float*)d_in[17];
    const float* b_lstm = (const float*)d_in[18];
    float* out = (float*)d_out;

    hipLaunchKernelGGL(uvfa_kernel, dim3(B_), dim3(NT), 0, stream,
                       state, obj, text, Ws1, bs1, Ws2, bs2, Ws3, bs3,
                       Wo1, bo1, Wo2, bo2, Wo3, bo3, emb, Wih, Whh, b_lstm, out);
}

// Round 9
// 39.337 us; speedup vs baseline: 1.9715x; 1.1886x over previous
//
#include <hip/hip_runtime.h>

// UVFA_text: B=256, M2=100, SV=OV=32, R=128, L=12, V=1000, E=64
// out[b,p] = sum_k relu(h2[p,k]+bs2[k]) * u[k] + bs3.w
//   h2[p,k] = relu(base_s + Ws1_pos[p]) @ Ws2[:,k]
//   w = obj_mlp(b) * lstm_h(b);  u[k] = Ws3[k,:] . w
// r9: P2 (x@Wih) and P8 (h1@Ws2) moved to MFMA (fragment mapping validated by
// r8's LSTM). LSTM MFMA + obj MLP kept from r8. 256 blocks x 1024 threads.

#define B_   256
#define M2_  100
#define R_   128
#define L_   12
#define E_   64
#define NT   1024

typedef _Float16 half2v __attribute__((ext_vector_type(2)));
typedef _Float16 f16x8  __attribute__((ext_vector_type(8)));
typedef float    f32x4  __attribute__((ext_vector_type(4)));

__device__ __forceinline__ float sigf(float x) { return 1.f / (1.f + expf(-x)); }

__device__ __forceinline__ uint pk16(float a, float b) {
    half2v h; h.x = (_Float16)a; h.y = (_Float16)b;
    return __builtin_bit_cast(uint, h);
}

__global__ __launch_bounds__(NT, 4) void uvfa_kernel(
    const int* __restrict__ state, const int* __restrict__ obj, const int* __restrict__ text,
    const float* __restrict__ Ws1, const float* __restrict__ bs1,
    const float* __restrict__ Ws2, const float* __restrict__ bs2,
    const float* __restrict__ Ws3, const float* __restrict__ bs3,
    const float* __restrict__ Wo1, const float* __restrict__ bo1,
    const float* __restrict__ Wo2, const float* __restrict__ bo2,
    const float* __restrict__ Wo3, const float* __restrict__ bo3,
    const float* __restrict__ emb, const float* __restrict__ Wih,
    const float* __restrict__ Whh, const float* __restrict__ b_lstm,
    float* __restrict__ out)
{
    const int b   = blockIdx.x;
    const int tid = threadIdx.x;

    // U (61.9 KiB union):
    //  phase A: xw f32 [16][512] = U[0..8191]; xemb f32 [16][66] = U[8192..9247]
    //  phase B: Ws2P u32 [64][132] = U[0..8447]; h1P u32 [112][66] = U[8448..15839]
    __shared__ __align__(16) uint  U[15840];
    __shared__ __align__(16) float part[NT];
    __shared__ __align__(16) float hbuf[R_];
    __shared__ __align__(16) uint  hpair[R_ / 2];
    __shared__ __align__(16) float tmp[R_], tmp2[R_], wbuf[R_], ubuf[R_], bsbuf[R_];
    __shared__ float redw2[2][112];
    __shared__ int   idx_o[M2_], idx_s[M2_], tids[L_];
    __shared__ float c0s;

    float* xw   = (float*)U;            // [16][512]
    float* xemb = (float*)(U + 8192);   // [16][66], rows 12..15 zero

    const int lane = tid & 63;
    const int wv   = tid >> 6;          // 0..15
    const int m16  = lane & 15;
    const int kgrp = lane >> 4;         // 0..3

    // ---------- LSTM A-fragments: Whh^T tiles in registers (r8, validated) ----------
    f16x8 af[2][4];
    #pragma unroll
    for (int tt = 0; tt < 2; ++tt) {
        int col = (2 * wv + tt) * 16 + m16;
        #pragma unroll
        for (int s = 0; s < 4; ++s) {
            int kb = s * 32 + kgrp * 8;
            #pragma unroll
            for (int e = 0; e < 8; ++e)
                af[tt][s][e] = (_Float16)Whh[(kb + e) * 512 + col];
        }
    }

    // ---------- P1: ids + init ----------
    if (tid < M2_) idx_o[tid] = obj[b * M2_ + tid];
    else if (tid >= 128 && tid < 128 + M2_) idx_s[tid - 128] = state[b * M2_ + tid - 128];
    else if (tid >= 256 && tid < 256 + L_) tids[tid - 256] = text[b * L_ + tid - 256];
    else if (tid >= 384 && tid < 448) hpair[tid - 384] = 0u;
    __syncthreads();
    if (tid < L_ * E_) xemb[(tid >> 6) * 66 + (tid & 63)] = emb[tids[tid >> 6] * E_ + (tid & 63)];
    else if (tid < L_ * E_ + 264) ((float*)(U + 8192 + 792))[tid - L_ * E_] = 0.f;  // rows 12..15
    __syncthreads();

    // ---------- P2: xw = b_lstm + x @ Wih via MFMA (wave = 2 col-tiles) ----------
    {
        f16x8 ax[2];
        #pragma unroll
        for (int s = 0; s < 2; ++s) {
            #pragma unroll
            for (int e = 0; e < 8; ++e)
                ax[s][e] = (_Float16)xemb[m16 * 66 + s * 32 + kgrp * 8 + e];
        }
        #pragma unroll
        for (int h = 0; h < 2; ++h) {
            int col = (wv * 2 + h) * 16 + m16;
            float bl = b_lstm[col];
            f32x4 acc = { bl, bl, bl, bl };
            #pragma unroll
            for (int s = 0; s < 2; ++s) {
                f16x8 bx;
                #pragma unroll
                for (int e = 0; e < 8; ++e)
                    bx[e] = (_Float16)Wih[(s * 32 + kgrp * 8 + e) * 512 + col];
                acc = __builtin_amdgcn_mfma_f32_16x16x32_f16(ax[s], bx, acc, 0, 0, 0);
            }
            if (kgrp < 3) {       // rows t = kgrp*4+reg < 12
                #pragma unroll
                for (int r = 0; r < 4; ++r)
                    xw[(kgrp * 4 + r) * 512 + col] = acc[r];
            }
        }
    }
    __syncthreads();

    // ---------- LSTM: 12 steps (r8, validated) ----------
    float cst = 0.f;
    for (int t = 0; t < L_; ++t) {
        f16x8 bf[4];
        #pragma unroll
        for (int s = 0; s < 4; ++s) {
            uint4 hb = *(const uint4*)&hpair[s * 16 + kgrp * 4];
            bf[s] = __builtin_bit_cast(f16x8, hb);
        }
        #pragma unroll
        for (int tt = 0; tt < 2; ++tt) {
            int colb = (2 * wv + tt) * 16 + kgrp * 4;
            f32x4 acc = *(const f32x4*)&xw[t * 512 + colb];
            #pragma unroll
            for (int s = 0; s < 4; ++s)
                acc = __builtin_amdgcn_mfma_f32_16x16x32_f16(af[tt][s], bf[s], acc, 0, 0, 0);
            if (m16 == 0) {
                part[colb + 0] = acc[0];
                part[colb + 1] = acc[1];
                part[colb + 2] = acc[2];
                part[colb + 3] = acc[3];
            }
        }
        __syncthreads();
        if (tid < R_) {
            float gi = part[tid], gf = part[R_ + tid], gg = part[2 * R_ + tid], go = part[3 * R_ + tid];
            cst = sigf(gf) * cst + sigf(gi) * tanhf(gg);
            float hn = sigf(go) * tanhf(cst);
            hbuf[tid] = hn;
            float hs = __shfl_down(hn, 1, 64);
            if (!(tid & 1)) hpair[tid >> 1] = pk16(hn, hs);
        }
        __syncthreads();
    }

    // ---------- stage Ws2P [64][132] f16-pairs (xw dead) ----------
    #pragma unroll
    for (int idx = tid; idx < 64 * 128; idx += NT) {
        int jp = idx >> 7, kk = idx & 127;
        U[jp * 132 + kk] = pk16(Ws2[(2 * jp) * R_ + kk], Ws2[(2 * jp + 1) * R_ + kk]);
    }

    // ---------- P4: object MLP (r8) ----------
    const int k = tid & 127, qq = tid >> 7;   // qq 0..7
    {
        float acc = 0.f;
        int c0i = qq * 13, c1i = c0i + 13 < M2_ ? c0i + 13 : M2_;
        for (int c = c0i; c < c1i; ++c)
            acc += Wo1[(c * 32 + idx_o[c]) * R_ + k];
        part[qq * R_ + k] = acc;
    }
    __syncthreads();
    if (tid < R_) {
        float a = bo1[tid];
        #pragma unroll
        for (int q8 = 0; q8 < 8; ++q8) a += part[q8 * R_ + tid];
        tmp[tid] = fmaxf(a, 0.f);
    }
    __syncthreads();
    {
        float s0 = 0.f, s1 = 0.f, s2 = 0.f, s3 = 0.f;
        int j0 = qq * 16;
        #pragma unroll
        for (int j = 0; j < 16; j += 4) {
            s0 = fmaf(tmp[j0 + j + 0], Wo2[(j0 + j + 0) * R_ + k], s0);
            s1 = fmaf(tmp[j0 + j + 1], Wo2[(j0 + j + 1) * R_ + k], s1);
            s2 = fmaf(tmp[j0 + j + 2], Wo2[(j0 + j + 2) * R_ + k], s2);
            s3 = fmaf(tmp[j0 + j + 3], Wo2[(j0 + j + 3) * R_ + k], s3);
        }
        part[qq * R_ + k] = (s0 + s1) + (s2 + s3);
    }
    __syncthreads();
    if (tid < R_) {
        float a = bo2[tid];
        #pragma unroll
        for (int q8 = 0; q8 < 8; ++q8) a += part[q8 * R_ + tid];
        tmp2[tid] = fmaxf(a, 0.f);
    }
    __syncthreads();
    {
        float s0 = 0.f, s1 = 0.f, s2 = 0.f, s3 = 0.f;
        int j0 = qq * 16;
        #pragma unroll
        for (int j = 0; j < 16; j += 4) {
            s0 = fmaf(tmp2[j0 + j + 0], Wo3[(j0 + j + 0) * R_ + k], s0);
            s1 = fmaf(tmp2[j0 + j + 1], Wo3[(j0 + j + 1) * R_ + k], s1);
            s2 = fmaf(tmp2[j0 + j + 2], Wo3[(j0 + j + 2) * R_ + k], s2);
            s3 = fmaf(tmp2[j0 + j + 3], Wo3[(j0 + j + 3) * R_ + k], s3);
        }
        part[qq * R_ + k] = (s0 + s1) + (s2 + s3);
    }
    __syncthreads();
    if (tid < R_) {
        float a = bo3[tid];
        #pragma unroll
        for (int q8 = 0; q8 < 8; ++q8) a += part[q8 * R_ + tid];
        wbuf[tid] = a * hbuf[tid];
    }
    __syncthreads();

    // ---------- P5: u = Ws3 @ w ; c0 = bs3 . w (r8) ----------
    {
        float s0 = 0.f, s1 = 0.f, s2 = 0.f, s3 = 0.f;
        int j0 = qq * 16;
        const float4* w3 = reinterpret_cast<const float4*>(&Ws3[k * R_ + j0]);
        #pragma unroll
        for (int jj = 0; jj < 4; ++jj) {
            float4 v = w3[jj];
            s0 = fmaf(v.x, wbuf[j0 + jj * 4 + 0], s0);
            s1 = fmaf(v.y, wbuf[j0 + jj * 4 + 1], s1);
            s2 = fmaf(v.z, wbuf[j0 + jj * 4 + 2], s2);
            s3 = fmaf(v.w, wbuf[j0 + jj * 4 + 3], s3);
        }
        part[qq * R_ + k] = (s0 + s1) + (s2 + s3);
    }
    if (tid >= 960) {
        int j = tid - 960;
        float s = bs3[j] * wbuf[j] + bs3[j + 64] * wbuf[j + 64];
        s += __shfl_down(s, 32, 64);
        s += __shfl_down(s, 16, 64);
        s += __shfl_down(s, 8, 64);
        s += __shfl_down(s, 4, 64);
        s += __shfl_down(s, 2, 64);
        s += __shfl_down(s, 1, 64);
        if (j == 0) c0s = s;
    }
    __syncthreads();
    if (tid < R_) {
        float a = 0.f;
        #pragma unroll
        for (int q8 = 0; q8 < 8; ++q8) a += part[q8 * R_ + tid];
        ubuf[tid] = a;
    }
    __syncthreads();

    // ---------- P6: base_s gather (r8) ----------
    {
        float acc = 0.f;
        int c0i = qq * 13, c1i = c0i + 13 < M2_ ? c0i + 13 : M2_;
        for (int c = c0i; c < c1i; ++c)
            acc += Ws1[(c * 33 + idx_s[c]) * R_ + k];
        part[qq * R_ + k] = acc;
    }
    __syncthreads();
    if (tid < R_) {
        float a = bs1[tid];
        #pragma unroll
        for (int q8 = 0; q8 < 8; ++q8) a += part[q8 * R_ + tid];
        bsbuf[tid] = a;
    }
    __syncthreads();

    // ---------- stage h1P [112][66] f16-pairs; zero rows 100..111 ----------
    #pragma unroll 4
    for (int pass = 0; pass < 13; ++pass) {
        int idx = pass * NT + tid;
        if (idx < M2_ * R_) {
            int j = idx & 127, p = idx >> 7;
            float v = fmaxf(bsbuf[j] + Ws1[(p * 33 + 32) * R_ + j], 0.f);
            float v2 = __shfl_down(v, 1, 64);
            if (!(j & 1)) U[8448 + p * 66 + (j >> 1)] = pk16(v, v2);
        }
    }
    if (tid < 792) U[8448 + 6600 + tid] = 0u;
    __syncthreads();

    // ---------- P8: h2 = h1 @ Ws2 via MFMA; wave = (mtile, nhalf) ----------
    if (wv < 14) {
        const int mtile = wv >> 1, nhalf = wv & 1;
        const uint* Ap = U + 8448 + (mtile * 16 + m16) * 66;
        f16x8 A[4];
        #pragma unroll
        for (int s = 0; s < 4; ++s) {
            int jb = s * 16 + kgrp * 4;
            uint4 av = { Ap[jb + 0], Ap[jb + 1], Ap[jb + 2], Ap[jb + 3] };
            A[s] = __builtin_bit_cast(f16x8, av);
        }
        f32x4 acc[4] = { {0,0,0,0}, {0,0,0,0}, {0,0,0,0}, {0,0,0,0} };
        #pragma unroll
        for (int nt = 0; nt < 4; ++nt) {
            int ko = (nhalf * 4 + nt) * 16 + m16;
            #pragma unroll
            for (int s = 0; s < 4; ++s) {
                const uint* Bp = U + (s * 16 + kgrp * 4) * 132 + ko;
                uint4 bv = { Bp[0], Bp[132], Bp[264], Bp[396] };
                acc[nt] = __builtin_amdgcn_mfma_f32_16x16x32_f16(
                    A[s], __builtin_bit_cast(f16x8, bv), acc[nt], 0, 0, 0);
            }
        }
        float vs0 = 0.f, vs1 = 0.f, vs2 = 0.f, vs3 = 0.f;
        #pragma unroll
        for (int nt = 0; nt < 4; ++nt) {
            int ko = (nhalf * 4 + nt) * 16 + m16;
            float bb = bs2[ko], uu = ubuf[ko];
            vs0 = fmaf(fmaxf(acc[nt][0] + bb, 0.f), uu, vs0);
            vs1 = fmaf(fmaxf(acc[nt][1] + bb, 0.f), uu, vs1);
            vs2 = fmaf(fmaxf(acc[nt][2] + bb, 0.f), uu, vs2);
            vs3 = fmaf(fmaxf(acc[nt][3] + bb, 0.f), uu, vs3);
        }
        vs0 += __shfl_xor(vs0, 1, 64); vs0 += __shfl_xor(vs0, 2, 64);
        vs0 += __shfl_xor(vs0, 4, 64); vs0 += __shfl_xor(vs0, 8, 64);
        vs1 += __shfl_xor(vs1, 1, 64); vs1 += __shfl_xor(vs1, 2, 64);
        vs1 += __shfl_xor(vs1, 4, 64); vs1 += __shfl_xor(vs1, 8, 64);
        vs2 += __shfl_xor(vs2, 1, 64); vs2 += __shfl_xor(vs2, 2, 64);
        vs2 += __shfl_xor(vs2, 4, 64); vs2 += __shfl_xor(vs2, 8, 64);
        vs3 += __shfl_xor(vs3, 1, 64); vs3 += __shfl_xor(vs3, 2, 64);
        vs3 += __shfl_xor(vs3, 4, 64); vs3 += __shfl_xor(vs3, 8, 64);
        if (m16 == 0) {
            int pr = mtile * 16 + kgrp * 4;
            redw2[nhalf][pr + 0] = vs0;
            redw2[nhalf][pr + 1] = vs1;
            redw2[nhalf][pr + 2] = vs2;
            redw2[nhalf][pr + 3] = vs3;
        }
    }
    __syncthreads();

    // ---------- final ----------
    if (tid < M2_)
        out[b * M2_ + tid] = c0s + redw2[0][tid] + redw2[1][tid];
}

extern "C" void kernel_launch(void* const* d_in, const int* in_sizes, int n_in,
                              void* d_out, int out_size, void* d_ws, size_t ws_size,
                              hipStream_t stream) {
    const int*   state  = (const int*)d_in[0];
    const int*   obj    = (const int*)d_in[1];
    const int*   text   = (const int*)d_in[2];
    const float* Ws1    = (const float*)d_in[3];
    const float* bs1    = (const float*)d_in[4];
    const float* Ws2    = (const float*)d_in[5];
    const float* bs2    = (const float*)d_in[6];
    const float* Ws3    = (const float*)d_in[7];
    const float* bs3    = (const float*)d_in[8];
    const float* Wo1    = (const float*)d_in[9];
    const float* bo1    = (const float*)d_in[10];
    const float* Wo2    = (const float*)d_in[11];
    const float* bo2    = (const float*)d_in[12];
    const float* Wo3    = (const float*)d_in[13];
    const float* bo3    = (const float*)d_in[14];
    const float* emb    = (const float*)d_in[15];
    const float* Wih    = (const float*)d_in[16];
    const float* Whh    = (const float*)d_in[17];
    const float* b_lstm = (const float*)d_in[18];
    float* out = (float*)d_out;

    hipLaunchKernelGGL(uvfa_kernel, dim3(B_), dim3(NT), 0, stream,
                       state, obj, text, Ws1, bs1, Ws2, bs2, Ws3, bs3,
                       Wo1, bo1, Wo2, bo2, Wo3, bo3, emb, Wih, Whh, b_lstm, out);
}